// Round 14
// baseline (877.748 us; speedup 1.0000x reference)
//
#include <hip/hip_runtime.h>
#include <hip/hip_bf16.h>
#include <math.h>

#define D_MODEL 1024
#define N_LAYERS 4
#define INTER 2048
#define D_CONV 4
#define D_STATE 16
#define DT_RANK 64
#define B_SZ 4
#define SEQ 1024
#define TOK (B_SZ*SEQ)          // 4096 token rows
#define XROWS 128               // x_proj rows padded 96 -> 128
#define EPSV 1e-5f
#define GCH 64                  // scan chunks
#define TC (SEQ/GCH)            // 16 timesteps per chunk
#define KSPL 8                  // x_proj K-split factor
#define OSPL 4                  // out_proj K-split factor (bf16 partials)

typedef unsigned short u16;
typedef unsigned int u32;
typedef __attribute__((ext_vector_type(8))) short bf16x8;
typedef __attribute__((ext_vector_type(4))) short s16x4;
typedef __attribute__((ext_vector_type(4))) float f32x4;

__device__ __forceinline__ u16 f2b(float f) {
    union { float f; unsigned u; } v; v.f = f;
    unsigned r = v.u + 0x7fffu + ((v.u >> 16) & 1u);
    return (u16)(r >> 16);
}
__device__ __forceinline__ float b2f(u16 h) {
    union { unsigned u; float f; } v; v.u = ((unsigned)h) << 16;
    return v.f;
}
__device__ __forceinline__ float silu(float x) {
    return x / (1.f + __expf(-x));
}
__device__ __forceinline__ void gload16(const void* g, void* l) {
    __builtin_amdgcn_global_load_lds(
        (const __attribute__((address_space(1))) void*)g,
        (__attribute__((address_space(3))) void*)l, 16, 0, 0);
}

// ---------------------------------------------------------------------------
// in_proj GEMM: 256x256 8-phase, BK=64, counted vmcnt, XCD swizzle,
// persistent fragments (R12/R13 structure — plateau ~44us, kept as-is).
// ---------------------------------------------------------------------------
__global__ __launch_bounds__(512, 2)
void gemm256_k(const u16* __restrict__ A, const u16* __restrict__ B,
               u16* __restrict__ C, int K, int ldc)
{
    __shared__ u16 lds[2][2][256 * 64];
    const int tid  = threadIdx.x;
    const int lane = tid & 63;
    const int wid  = tid >> 6;
    const int wr   = wid >> 2;
    const int wc   = wid & 3;
    const int hwid = blockIdx.y * gridDim.x + blockIdx.x;     // 0..255
    const int work = (hwid & 7) * 32 + (hwid >> 3);           // XCD swizzle
    const int row0 = (work >> 4) * 256;
    const int col0 = (work & 15) * 256;
    const int r16   = lane & 15;
    const int khalf = lane >> 4;

    auto ld1 = [&](int buf, int k0, int l) {
        int op = l >> 2;
        int c  = tid + (l & 3) * 512;
        int r  = c >> 3;
        int ds = c & 7;
        int sc = (ds ^ (r & 7)) * 8;
        const u16* src = op ? &B[(size_t)(col0 + r) * K + k0 + sc]
                            : &A[(size_t)(row0 + r) * K + k0 + sc];
        gload16(src, &lds[buf][op][c * 8]);
    };
    // pairs: 0:{A0,A2} 1:{B0,B1} 2:{B2,B3} 3:{A1,A3}
    auto stage2 = [&](int buf, int k0, int pair) {
        if (pair == 0)      { ld1(buf, k0, 0); ld1(buf, k0, 2); }
        else if (pair == 1) { ld1(buf, k0, 4); ld1(buf, k0, 5); }
        else if (pair == 2) { ld1(buf, k0, 6); ld1(buf, k0, 7); }
        else                { ld1(buf, k0, 1); ld1(buf, k0, 3); }
    };
    auto rdA = [&](int buf, int mrow, int ks) -> bf16x8 {
        int row  = wr * 128 + mrow + r16;
        int phys = ((ks << 2) | khalf) ^ (row & 7);
        return *(const bf16x8*)&lds[buf][0][row * 64 + phys * 8];
    };
    auto rdB = [&](int buf, int nrow, int ks) -> bf16x8 {
        int row  = wc * 64 + nrow + r16;
        int phys = ((ks << 2) | khalf) ^ (row & 7);
        return *(const bf16x8*)&lds[buf][1][row * 64 + phys * 8];
    };

    f32x4 acc[8][4];
#pragma unroll
    for (int m = 0; m < 8; ++m)
#pragma unroll
        for (int n = 0; n < 4; ++n)
            acc[m][n] = (f32x4)0.f;

    bf16x8 afA[4][2], afB[4][2], b01[2][2], b23[2][2];

#define PHASE_MFMA(MH, NH, AF, BF) do {                                       \
    asm volatile("s_waitcnt lgkmcnt(0)" ::: "memory");                        \
    __builtin_amdgcn_sched_barrier(0);                                        \
    __builtin_amdgcn_s_setprio(1);                                            \
    _Pragma("unroll")                                                         \
    for (int ks = 0; ks < 2; ++ks)                                            \
        _Pragma("unroll")                                                     \
        for (int m = 0; m < 4; ++m)                                           \
            _Pragma("unroll")                                                 \
            for (int n = 0; n < 2; ++n)                                       \
                acc[(MH)*4+m][(NH)*2+n] =                                     \
                    __builtin_amdgcn_mfma_f32_16x16x32_bf16(                  \
                        AF[m][ks], BF[n][ks], acc[(MH)*4+m][(NH)*2+n],0,0,0); \
    __builtin_amdgcn_s_setprio(0);                                            \
} while (0)

    const int nt = K >> 6;
    stage2(0, 0, 0); stage2(0, 0, 1); stage2(0, 0, 3); stage2(0, 0, 2);
    asm volatile("s_waitcnt vmcnt(4)" ::: "memory");
    __builtin_amdgcn_s_barrier();

    for (int j = 0; j < nt; ++j) {
        const int buf = j & 1;
        const int nb  = buf ^ 1;
        const int k1  = (j + 1) << 6;
        const bool pf = (j + 1 < nt);
        // phase 0: quadrant (0,0); read afA + B01; issue p0^{j+1}
        if (pf) stage2(nb, k1, 0);
#pragma unroll
        for (int m = 0; m < 4; ++m) {
            afA[m][0] = rdA(buf, m * 16, 0); afA[m][1] = rdA(buf, m * 16, 1);
        }
#pragma unroll
        for (int n = 0; n < 2; ++n) {
            b01[n][0] = rdB(buf, n * 16, 0); b01[n][1] = rdB(buf, n * 16, 1);
        }
        __builtin_amdgcn_s_barrier();
        PHASE_MFMA(0, 0, afA, b01);
        if (pf) { asm volatile("s_waitcnt vmcnt(4)" ::: "memory"); }  // p3^j
        else    { asm volatile("s_waitcnt vmcnt(2)" ::: "memory"); }
        __builtin_amdgcn_s_barrier();
        // phase 1: quadrant (1,0); read afB; issue p1^{j+1}
        if (pf) stage2(nb, k1, 1);
#pragma unroll
        for (int m = 0; m < 4; ++m) {
            afB[m][0] = rdA(buf, 64 + m * 16, 0); afB[m][1] = rdA(buf, 64 + m * 16, 1);
        }
        __builtin_amdgcn_s_barrier();
        PHASE_MFMA(1, 0, afB, b01);
        if (pf) { asm volatile("s_waitcnt vmcnt(4)" ::: "memory"); }  // p2^j
        else    { asm volatile("s_waitcnt vmcnt(0)" ::: "memory"); }
        __builtin_amdgcn_s_barrier();
        // phase 2: quadrant (1,1); read B23; issue p3^{j+1}
        if (pf) stage2(nb, k1, 3);
#pragma unroll
        for (int n = 0; n < 2; ++n) {
            b23[n][0] = rdB(buf, 32 + n * 16, 0); b23[n][1] = rdB(buf, 32 + n * 16, 1);
        }
        __builtin_amdgcn_s_barrier();
        PHASE_MFMA(1, 1, afB, b23);
        __builtin_amdgcn_s_barrier();
        // phase 3: quadrant (0,1); no reads; issue p2^{j+1}
        if (pf) stage2(nb, k1, 2);
        PHASE_MFMA(0, 1, afA, b23);
        if (pf) { asm volatile("s_waitcnt vmcnt(4)" ::: "memory"); }  // p0,p1
        __builtin_amdgcn_s_barrier();
    }
#undef PHASE_MFMA

    const int orow = row0 + wr * 128;
    const int ocol = col0 + wc * 64;
#pragma unroll
    for (int am = 0; am < 8; ++am)
#pragma unroll
        for (int an = 0; an < 4; ++an)
#pragma unroll
            for (int r = 0; r < 4; ++r) {
                int rr = orow + am * 16 + khalf * 4 + r;
                int cc = ocol + an * 16 + r16;
                C[(size_t)rr * ldc + cc] = f2b(acc[am][an][r]);
            }
}

// ---------------------------------------------------------------------------
// 128x128 GEMM: 3-buffer pipeline, swizzled.
// EPI: 0 = fp32, 2 = softplus(acc+aux[col])->bf16,
//      4 = split-K partial fp32, 5 = split-K partial bf16
//      (4/5: part = blockIdx.x / NPX, col-tile = % NPX, C += part*pstride)
// ---------------------------------------------------------------------------
template<int EPI, int NPX = 1>
__global__ __launch_bounds__(256)
void gemm_bt(const u16* __restrict__ A, const u16* __restrict__ B,
             void* __restrict__ C, const float* __restrict__ aux,
             int K, int lda, int ldc, size_t pstride)
{
    __shared__ u16 As[3][128 * 32];
    __shared__ u16 Bs[3][128 * 32];
    const int tid  = threadIdx.x;
    const int lane = tid & 63;
    const int w    = tid >> 6;
    const int wr   = w >> 1, wc = w & 1;
    const int row0 = blockIdx.y * 128;
    int col0 = blockIdx.x * 128;
    if (EPI == 4 || EPI == 5) {
        int part = blockIdx.x / NPX;
        col0 = (blockIdx.x % NPX) * 128;
        A += (size_t)part * K;
        B += (size_t)part * K;
        if (EPI == 4) C = (void*)((float*)C + (size_t)part * pstride);
        else          C = (void*)((u16*)C   + (size_t)part * pstride);
    }
    const int r16   = lane & 15;
    const int khalf = lane >> 4;
    const int kslot = khalf ^ ((r16 >> 1) & 3);

    auto stage = [&](int buf, int k0) {
#pragma unroll
        for (int c = 0; c < 2; ++c) {
            int chunk = tid + c * 256;
            int r  = chunk >> 2;
            int j  = chunk & 3;
            int k8 = (j ^ ((r >> 1) & 3)) * 8;
            gload16(&A[(size_t)(row0 + r) * lda + k0 + k8], &As[buf][chunk * 8]);
            gload16(&B[(size_t)(col0 + r) * lda + k0 + k8], &Bs[buf][chunk * 8]);
        }
    };

    f32x4 acc[4][4];
#pragma unroll
    for (int m = 0; m < 4; ++m)
#pragma unroll
        for (int n = 0; n < 4; ++n)
            acc[m][n] = (f32x4)0.f;

    const int nt = K >> 5;
    stage(0, 0);
    if (nt > 1) stage(1, 32);

    int cur = 0, sb = 2;
    for (int t = 0; t < nt; ++t) {
        if (t + 2 < nt) {
            stage(sb, (t + 2) << 5);
            asm volatile("s_waitcnt vmcnt(8)" ::: "memory");
        } else if (t + 1 < nt) {
            asm volatile("s_waitcnt vmcnt(4)" ::: "memory");
        } else {
            asm volatile("s_waitcnt vmcnt(0)" ::: "memory");
        }
        __builtin_amdgcn_s_barrier();

        bf16x8 af[4], bfr[4];
#pragma unroll
        for (int m = 0; m < 4; ++m)
            af[m]  = *(const bf16x8*)&As[cur][(wr * 64 + m * 16 + r16) * 32 + kslot * 8];
#pragma unroll
        for (int n = 0; n < 4; ++n)
            bfr[n] = *(const bf16x8*)&Bs[cur][(wc * 64 + n * 16 + r16) * 32 + kslot * 8];
#pragma unroll
        for (int m = 0; m < 4; ++m)
#pragma unroll
            for (int n = 0; n < 4; ++n)
                acc[m][n] = __builtin_amdgcn_mfma_f32_16x16x32_bf16(
                    af[m], bfr[n], acc[m][n], 0, 0, 0);

        __builtin_amdgcn_sched_barrier(0);
        asm volatile("s_waitcnt lgkmcnt(0)" ::: "memory");
        __builtin_amdgcn_s_barrier();
        cur = (cur == 2) ? 0 : cur + 1;
        sb  = (sb  == 2) ? 0 : sb  + 1;
    }

    const int orow = row0 + wr * 64;
    const int ocol = col0 + wc * 64;
#pragma unroll
    for (int m = 0; m < 4; ++m)
#pragma unroll
        for (int n = 0; n < 4; ++n) {
#pragma unroll
            for (int r = 0; r < 4; ++r) {
                int rr = orow + m * 16 + khalf * 4 + r;
                int cc = ocol + n * 16 + r16;
                float v = acc[m][n][r];
                size_t o = (size_t)rr * ldc + cc;
                if (EPI == 0 || EPI == 4) {
                    ((float*)C)[o] = v;
                } else if (EPI == 5) {
                    ((u16*)C)[o] = f2b(v);
                } else if (EPI == 2) {
                    float x = v + aux[cc];
                    float sp = (x > 20.f) ? x : log1pf(__expf(x));
                    ((u16*)C)[o] = f2b(sp);
                }
            }
        }
}

// ---------------------------------------------------------------------------
// x_proj split-K reduce: ssm = sum of KSPL fp32 partials + bf16 dt-rank cols.
// ---------------------------------------------------------------------------
__global__ __launch_bounds__(256)
void xred_k(const float* __restrict__ part, float* __restrict__ ssm,
            u16* __restrict__ dtr)
{
    int idx = blockIdx.x * 256 + threadIdx.x;
    int row = idx >> 5;
    int col = (idx & 31) * 4;
    size_t o = (size_t)row * XROWS + col;
    const size_t stride = (size_t)TOK * XROWS;
    f32x4 v = *(const f32x4*)&part[o];
#pragma unroll
    for (int p = 1; p < KSPL; ++p)
        v += *(const f32x4*)&part[o + p * stride];
    *(f32x4*)&ssm[o] = v;
    if (col < DT_RANK) {
        s16x4 d;
#pragma unroll
        for (int j = 0; j < 4; ++j) d[j] = (short)f2b(v[j]);
        *(s16x4*)&dtr[(size_t)row * DT_RANK + col] = d;
    }
}

// ---------------------------------------------------------------------------
// RMSNorm (plain): rows of 1024 fp32 -> bf16/fp32.
// ---------------------------------------------------------------------------
template<int OUTBF>
__global__ __launch_bounds__(256)
void rmsnorm_k(const float* __restrict__ in, const float* __restrict__ w,
               void* __restrict__ out)
{
    __shared__ float red[4];
    const int row = blockIdx.x;
    const int tid = threadIdx.x;
    const float* r = in + (size_t)row * D_MODEL;
    f32x4 v = *(const f32x4*)&r[tid * 4];
    float ss = v[0]*v[0] + v[1]*v[1] + v[2]*v[2] + v[3]*v[3];
#pragma unroll
    for (int m = 32; m >= 1; m >>= 1) ss += __shfl_xor(ss, m, 64);
    if ((tid & 63) == 0) red[tid >> 6] = ss;
    __syncthreads();
    if (tid == 0) {
        float s = red[0] + red[1] + red[2] + red[3];
        red[0] = rsqrtf(s / (float)D_MODEL + EPSV);
    }
    __syncthreads();
    float sc = red[0];
    if (OUTBF) {
        u16* o = (u16*)out + (size_t)row * D_MODEL + tid * 4;
#pragma unroll
        for (int j = 0; j < 4; ++j) o[j] = f2b(v[j] * sc * w[tid * 4 + j]);
    } else {
        float* o = (float*)out + (size_t)row * D_MODEL + tid * 4;
#pragma unroll
        for (int j = 0; j < 4; ++j) o[j] = v[j] * sc * w[tid * 4 + j];
    }
}

// ---------------------------------------------------------------------------
// Fused residual + RMSNorm: hn = hin + sum of OSPL bf16 partials;
// optionally write hn to hout; write normalized output (bf16 or fp32).
// ---------------------------------------------------------------------------
template<int OUTBF, int WRITEH>
__global__ __launch_bounds__(256)
void rmsnorm_res_k(const float* __restrict__ hin, const u16* __restrict__ p,
                   const float* __restrict__ w, float* __restrict__ hout,
                   void* __restrict__ out)
{
    __shared__ float red[4];
    const int row = blockIdx.x;
    const int tid = threadIdx.x;
    const size_t o4 = (size_t)row * D_MODEL + tid * 4;
    f32x4 v = *(const f32x4*)&hin[o4];
#pragma unroll
    for (int k = 0; k < OSPL; ++k) {
        s16x4 pv = *(const s16x4*)&p[(size_t)k * TOK * D_MODEL + o4];
#pragma unroll
        for (int j = 0; j < 4; ++j) v[j] += b2f((u16)pv[j]);
    }
    if (WRITEH) *(f32x4*)&hout[o4] = v;
    float ss = v[0]*v[0] + v[1]*v[1] + v[2]*v[2] + v[3]*v[3];
#pragma unroll
    for (int m = 32; m >= 1; m >>= 1) ss += __shfl_xor(ss, m, 64);
    if ((tid & 63) == 0) red[tid >> 6] = ss;
    __syncthreads();
    if (tid == 0) {
        float s = red[0] + red[1] + red[2] + red[3];
        red[0] = rsqrtf(s / (float)D_MODEL + EPSV);
    }
    __syncthreads();
    float sc = red[0];
    if (OUTBF) {
        u16* o = (u16*)out + o4;
#pragma unroll
        for (int j = 0; j < 4; ++j) o[j] = f2b(v[j] * sc * w[tid * 4 + j]);
    } else {
        float* o = (float*)out + o4;
#pragma unroll
        for (int j = 0; j < 4; ++j) o[j] = v[j] * sc * w[tid * 4 + j];
    }
}

// ---------------------------------------------------------------------------
// Depthwise causal conv + bias + SiLU, sliding window (4 tokens/block).
// ---------------------------------------------------------------------------
__global__ __launch_bounds__(256)
void conv_silu_k(const u16* __restrict__ projbf, const float* __restrict__ w,
                 const float* __restrict__ bias, u16* __restrict__ ubf)
{
    const int tok0 = blockIdx.x * 4;
    const int t0   = tok0 & (SEQ - 1);
    const int i0   = threadIdx.x * 8;
    float hv[7][8];
#pragma unroll
    for (int m = 0; m < 7; ++m) {
        int tt = t0 - 3 + m;
        if (tt >= 0) {
            bf16x8 v = *(const bf16x8*)&projbf[(size_t)(tok0 - 3 + m) * 4096 + i0];
#pragma unroll
            for (int j = 0; j < 8; ++j) hv[m][j] = b2f((u16)v[j]);
        } else {
#pragma unroll
            for (int j = 0; j < 8; ++j) hv[m][j] = 0.f;
        }
    }
    f32x4 wv[8];
#pragma unroll
    for (int j = 0; j < 8; ++j)
        wv[j] = *(const f32x4*)&w[(i0 + j) * 4];
    float bs[8];
    {
        f32x4 b0 = *(const f32x4*)&bias[i0];
        f32x4 b1 = *(const f32x4*)&bias[i0 + 4];
#pragma unroll
        for (int j = 0; j < 4; ++j) { bs[j] = b0[j]; bs[j + 4] = b1[j]; }
    }
#pragma unroll
    for (int q = 0; q < 4; ++q) {
        bf16x8 o;
#pragma unroll
        for (int j = 0; j < 8; ++j) {
            float acc = bs[j];
#pragma unroll
            for (int k = 0; k < 4; ++k)
                acc += hv[q + k][j] * wv[j][k];
            o[j] = (short)f2b(silu(acc));
        }
        *(bf16x8*)&ubf[(size_t)(tok0 + q) * INTER + i0] = o;
    }
}

// ---------------------------------------------------------------------------
// A_log structure check (fast-path guard).
// ---------------------------------------------------------------------------
__global__ __launch_bounds__(256)
void achk_k(const float* __restrict__ Alog, int* __restrict__ flags)
{
    int idx = blockIdx.x * 256 + threadIdx.x;
    if (idx >= N_LAYERS * INTER * D_STATE) return;
    int l = idx / (INTER * D_STATE);
    int n = idx & (D_STATE - 1);
    float ref = logf((float)(n + 1));
    if (fabsf(Alog[idx] - ref) > 1e-4f) atomicAnd(&flags[l], 0);
}

// ---------------------------------------------------------------------------
// Chunked selective scan, 2 channels per thread (ILP x2, packed u32 loads).
// Fast path: decay exp(dt*a_n) == w^(n+1), w = exp(-dt).
// ---------------------------------------------------------------------------
#define POWCH(W, p) \
    float p##2=(W)*(W), p##3=p##2*(W), p##4=p##2*p##2, p##5=p##4*(W),        \
          p##6=p##4*p##2, p##7=p##4*p##3, p##8=p##4*p##4, p##9=p##8*(W),     \
          p##10=p##8*p##2, p##11=p##8*p##3, p##12=p##8*p##4, p##13=p##8*p##5,\
          p##14=p##8*p##6, p##15=p##8*p##7, p##16=p##8*p##8;

#define SUPD(S, B, du, w1) \
    S[0]=w1*S[0]+du*B[0][0];   S[1]=w1##2*S[1]+du*B[0][1];                   \
    S[2]=w1##3*S[2]+du*B[0][2];  S[3]=w1##4*S[3]+du*B[0][3];                 \
    S[4]=w1##5*S[4]+du*B[1][0];  S[5]=w1##6*S[5]+du*B[1][1];                 \
    S[6]=w1##7*S[6]+du*B[1][2];  S[7]=w1##8*S[7]+du*B[1][3];                 \
    S[8]=w1##9*S[8]+du*B[2][0];  S[9]=w1##10*S[9]+du*B[2][1];                \
    S[10]=w1##11*S[10]+du*B[2][2]; S[11]=w1##12*S[11]+du*B[2][3];            \
    S[12]=w1##13*S[12]+du*B[3][0]; S[13]=w1##14*S[13]+du*B[3][1];            \
    S[14]=w1##15*S[14]+du*B[3][2]; S[15]=w1##16*S[15]+du*B[3][3];

#define YDOT(S, Cv) \
    (S[0]*Cv[0][0]+S[1]*Cv[0][1]+S[2]*Cv[0][2]+S[3]*Cv[0][3]                 \
    +S[4]*Cv[1][0]+S[5]*Cv[1][1]+S[6]*Cv[1][2]+S[7]*Cv[1][3]                 \
    +S[8]*Cv[2][0]+S[9]*Cv[2][1]+S[10]*Cv[2][2]+S[11]*Cv[2][3]               \
    +S[12]*Cv[3][0]+S[13]*Cv[3][1]+S[14]*Cv[3][2]+S[15]*Cv[3][3])

__global__ __launch_bounds__(256)
void scan1_k(const u16* __restrict__ dtbf, const u16* __restrict__ ubf,
             const float* __restrict__ ssm, const float* __restrict__ Alog,
             const int* __restrict__ flag,
             float* __restrict__ cst, float* __restrict__ dts)
{
    __shared__ float Bsh[TC][D_STATE];
    const int tid = threadIdx.x;
    const int i2  = blockIdx.x * 256 + tid;     // channel pair index
    const int c0  = i2 * 2;
    const int g   = blockIdx.y;
    const int b   = blockIdx.z;
    const int t0  = g * TC;
    {
        int t = tid >> 4, n = tid & 15;        // TC*16 = 256
        Bsh[t][n] = ssm[(size_t)(b * SEQ + t0 + t) * XROWS + DT_RANK + n];
    }
    __syncthreads();

    float s0[D_STATE], s1[D_STATE];
#pragma unroll
    for (int n = 0; n < D_STATE; ++n) { s0[n] = 0.f; s1[n] = 0.f; }
    float ds0 = 0.f, ds1 = 0.f;

    const u32* dtp = (const u32*)dtbf + ((size_t)(b * SEQ + t0) * INTER >> 1) + i2;
    const u32* up  = (const u32*)ubf  + ((size_t)(b * SEQ + t0) * INTER >> 1) + i2;

    if (flag[0]) {
#pragma unroll
        for (int t = 0; t < TC; ++t) {
            u32 dp = dtp[(size_t)t * (INTER / 2)];
            u32 uq = up[(size_t)t * (INTER / 2)];
            float dta = b2f((u16)dp), dtb = b2f((u16)(dp >> 16));
            float ua  = b2f((u16)uq), ub  = b2f((u16)(uq >> 16));
            float dua = dta * ua, dub = dtb * ub;
            ds0 += dta; ds1 += dtb;
            float wa = __expf(-dta), wb = __expf(-dtb);
            POWCH(wa, wa) POWCH(wb, wb)
            f32x4 Bq[4];
#pragma unroll
            for (int q = 0; q < 4; ++q) Bq[q] = *(const f32x4*)&Bsh[t][q * 4];
            SUPD(s0, Bq, dua, wa)
            SUPD(s1, Bq, dub, wb)
        }
    } else {
        float a0[D_STATE], a1[D_STATE];
#pragma unroll
        for (int n = 0; n < D_STATE; ++n) {
            a0[n] = -__expf(Alog[(size_t)c0 * D_STATE + n]);
            a1[n] = -__expf(Alog[(size_t)(c0 + 1) * D_STATE + n]);
        }
        for (int t = 0; t < TC; ++t) {
            u32 dp = dtp[(size_t)t * (INTER / 2)];
            u32 uq = up[(size_t)t * (INTER / 2)];
            float dta = b2f((u16)dp), dtb = b2f((u16)(dp >> 16));
            float ua  = b2f((u16)uq), ub  = b2f((u16)(uq >> 16));
            float dua = dta * ua, dub = dtb * ub;
            ds0 += dta; ds1 += dtb;
#pragma unroll
            for (int n = 0; n < D_STATE; ++n) {
                float Bn = Bsh[t][n];
                s0[n] = __expf(dta * a0[n]) * s0[n] + dua * Bn;
                s1[n] = __expf(dtb * a1[n]) * s1[n] + dub * Bn;
            }
        }
    }
    size_t o = ((size_t)(b * GCH + g) * INTER + c0) * D_STATE;
#pragma unroll
    for (int n = 0; n < D_STATE; n += 4) {
        f32x4 v0 = { s0[n], s0[n+1], s0[n+2], s0[n+3] };
        f32x4 v1 = { s1[n], s1[n+1], s1[n+2], s1[n+3] };
        *(f32x4*)&cst[o + n] = v0;
        *(f32x4*)&cst[o + D_STATE + n] = v1;
    }
    size_t od = (size_t)(b * GCH + g) * INTER + c0;
    dts[od] = ds0; dts[od + 1] = ds1;
}

// in-place: cst local chunk-end -> chunk-START states.
__global__ __launch_bounds__(256)
void scan2_k(float* __restrict__ cst, const float* __restrict__ dts,
             const float* __restrict__ Alog)
{
    int idx = blockIdx.x * 256 + threadIdx.x;
    int sub = idx & 3;
    int i   = (idx >> 2) & (INTER - 1);
    int b   = idx >> 13;
    int n0  = sub * 4;
    float a[4];
#pragma unroll
    for (int n = 0; n < 4; ++n)
        a[n] = -__expf(Alog[(size_t)i * D_STATE + n0 + n]);
    f32x4 s = (f32x4)0.f;
    for (int g = 0; g < GCH; ++g) {
        size_t o = ((size_t)(b * GCH + g) * INTER + i) * D_STATE + n0;
        f32x4 tmp = *(const f32x4*)&cst[o];
        *(f32x4*)&cst[o] = s;
        float d = dts[(size_t)(b * GCH + g) * INTER + i];
#pragma unroll
        for (int n = 0; n < 4; ++n)
            s[n] = __expf(a[n] * d) * s[n] + tmp[n];
    }
}

__global__ __launch_bounds__(256)
void scan3_k(const u16* __restrict__ dtbf, const u16* __restrict__ ubf,
             const float* __restrict__ ssm, const u16* __restrict__ projbf,
             const float* __restrict__ Alog, const float* __restrict__ Dp,
             const int* __restrict__ flag,
             const float* __restrict__ sst, u16* __restrict__ ybf)
{
    __shared__ float Bsh[TC][D_STATE];
    __shared__ float Csh[TC][D_STATE];
    const int tid = threadIdx.x;
    const int i2  = blockIdx.x * 256 + tid;
    const int c0  = i2 * 2;
    const int g   = blockIdx.y;
    const int b   = blockIdx.z;
    const int t0  = g * TC;
    {
        int t = tid >> 4, n = tid & 15;
        size_t row = (size_t)(b * SEQ + t0 + t) * XROWS;
        Bsh[t][n] = ssm[row + DT_RANK + n];
        Csh[t][n] = ssm[row + DT_RANK + D_STATE + n];
    }
    __syncthreads();

    const float Da = Dp[c0], Db = Dp[c0 + 1];
    float s0[D_STATE], s1[D_STATE];
    size_t so = ((size_t)(b * GCH + g) * INTER + c0) * D_STATE;
#pragma unroll
    for (int n = 0; n < D_STATE; n += 4) {
        f32x4 v0 = *(const f32x4*)&sst[so + n];
        f32x4 v1 = *(const f32x4*)&sst[so + D_STATE + n];
        s0[n] = v0[0]; s0[n+1] = v0[1]; s0[n+2] = v0[2]; s0[n+3] = v0[3];
        s1[n] = v1[0]; s1[n+1] = v1[1]; s1[n+2] = v1[2]; s1[n+3] = v1[3];
    }

    const u32* dtp = (const u32*)dtbf + ((size_t)(b * SEQ + t0) * INTER >> 1) + i2;
    const u32* up  = (const u32*)ubf  + ((size_t)(b * SEQ + t0) * INTER >> 1) + i2;
    const u32* gp  = (const u32*)projbf + (((size_t)(b * SEQ + t0) * 4096 + INTER) >> 1) + i2;
    u32*       yp  = (u32*)ybf + ((size_t)(b * SEQ + t0) * INTER >> 1) + i2;

    if (flag[0]) {
#pragma unroll
        for (int t = 0; t < TC; ++t) {
            u32 dp = dtp[(size_t)t * (INTER / 2)];
            u32 uq = up[(size_t)t * (INTER / 2)];
            u32 gq = gp[(size_t)t * (4096 / 2)];
            float dta = b2f((u16)dp), dtb = b2f((u16)(dp >> 16));
            float ua  = b2f((u16)uq), ub  = b2f((u16)(uq >> 16));
            float ga  = b2f((u16)gq), gb  = b2f((u16)(gq >> 16));
            float dua = dta * ua, dub = dtb * ub;
            float wa = __expf(-dta), wb = __expf(-dtb);
            POWCH(wa, wa) POWCH(wb, wb)
            f32x4 Bq[4], Cq[4];
#pragma unroll
            for (int q = 0; q < 4; ++q) {
                Bq[q] = *(const f32x4*)&Bsh[t][q * 4];
                Cq[q] = *(const f32x4*)&Csh[t][q * 4];
            }
            SUPD(s0, Bq, dua, wa)
            SUPD(s1, Bq, dub, wb)
            float y0 = YDOT(s0, Cq);
            float y1 = YDOT(s1, Cq);
            y0 = (y0 + Da * ua) * silu(ga);
            y1 = (y1 + Db * ub) * silu(gb);
            yp[(size_t)t * (INTER / 2)] = (u32)f2b(y0) | ((u32)f2b(y1) << 16);
        }
    } else {
        float a0[D_STATE], a1[D_STATE];
#pragma unroll
        for (int n = 0; n < D_STATE; ++n) {
            a0[n] = -__expf(Alog[(size_t)c0 * D_STATE + n]);
            a1[n] = -__expf(Alog[(size_t)(c0 + 1) * D_STATE + n]);
        }
        for (int t = 0; t < TC; ++t) {
            u32 dp = dtp[(size_t)t * (INTER / 2)];
            u32 uq = up[(size_t)t * (INTER / 2)];
            u32 gq = gp[(size_t)t * (4096 / 2)];
            float dta = b2f((u16)dp), dtb = b2f((u16)(dp >> 16));
            float ua  = b2f((u16)uq), ub  = b2f((u16)(uq >> 16));
            float ga  = b2f((u16)gq), gb  = b2f((u16)(gq >> 16));
            float dua = dta * ua, dub = dtb * ub;
            float y0 = 0.f, y1 = 0.f;
#pragma unroll
            for (int n = 0; n < D_STATE; ++n) {
                float Bn = Bsh[t][n], Cn = Csh[t][n];
                s0[n] = __expf(dta * a0[n]) * s0[n] + dua * Bn;
                s1[n] = __expf(dtb * a1[n]) * s1[n] + dub * Bn;
                y0 += s0[n] * Cn; y1 += s1[n] * Cn;
            }
            y0 = (y0 + Da * ua) * silu(ga);
            y1 = (y1 + Db * ub) * silu(gb);
            yp[(size_t)t * (INTER / 2)] = (u32)f2b(y0) | ((u32)f2b(y1) << 16);
        }
    }
}

// ---------------------------------------------------------------------------
// Merged weight conversion fp32 -> bf16 (inw | dtw | outw | xw-pad).
// ---------------------------------------------------------------------------
#define INW_N  (N_LAYERS * 4096 * 1024)
#define DTW_N  (N_LAYERS * INTER * DT_RANK)
#define OUTW_N (N_LAYERS * D_MODEL * INTER)
#define XWP_N  (N_LAYERS * XROWS * INTER)
__global__ __launch_bounds__(256)
void cvtall_k(const float* __restrict__ in_w, const float* __restrict__ dt_w,
              const float* __restrict__ out_w, const float* __restrict__ xw,
              u16* __restrict__ inw_bf, u16* __restrict__ dtw_bf,
              u16* __restrict__ outw_bf, u16* __restrict__ xw_bf)
{
    int idx = (blockIdx.x * 256 + threadIdx.x) * 4;
    const float* src;
    u16* dst;
    int i;
    if (idx < INW_N) {
        src = in_w; dst = inw_bf; i = idx;
    } else if (idx < INW_N + DTW_N) {
        src = dt_w; dst = dtw_bf; i = idx - INW_N;
    } else if (idx < INW_N + DTW_N + OUTW_N) {
        src = out_w; dst = outw_bf; i = idx - INW_N - DTW_N;
    } else {
        i = idx - INW_N - DTW_N - OUTW_N;
        if (i >= XWP_N) return;
        int l = i / (XROWS * INTER);
        int r = (i >> 11) & (XROWS - 1);
        int c = i & (INTER - 1);
        s16x4 d;
        if (r < 96) {
            f32x4 v = *(const f32x4*)&xw[((size_t)l * 96 + r) * INTER + c];
#pragma unroll
            for (int j = 0; j < 4; ++j) d[j] = (short)f2b(v[j]);
        } else {
            d = (s16x4)0;
        }
        *(s16x4*)&xw_bf[i] = d;
        return;
    }
    f32x4 v = *(const f32x4*)&src[i];
    s16x4 d;
#pragma unroll
    for (int j = 0; j < 4; ++j) d[j] = (short)f2b(v[j]);
    *(s16x4*)&dst[i] = d;
}

// ---------------------------------------------------------------------------
extern "C" void kernel_launch(void* const* d_in, const int* in_sizes, int n_in,
                              void* d_out, int out_size, void* d_ws, size_t ws_size,
                              hipStream_t stream)
{
    const float* x      = (const float*)d_in[0];
    const float* in_w   = (const float*)d_in[1];
    const float* conv_w = (const float*)d_in[2];
    const float* conv_b = (const float*)d_in[3];
    const float* x_w    = (const float*)d_in[4];
    const float* dt_w   = (const float*)d_in[5];
    const float* dt_b   = (const float*)d_in[6];
    const float* A_log  = (const float*)d_in[7];
    const float* Dp     = (const float*)d_in[8];
    const float* out_w  = (const float*)d_in[9];
    const float* norm_w = (const float*)d_in[10];
    const float* norm_f = (const float*)d_in[11];

    char* ws = (char*)d_ws;
    size_t off = 0;
    auto alloc = [&](size_t bytes) { char* p = ws + off; off += (bytes + 255) & ~(size_t)255; return p; };

    u16*   inw_bf  = (u16*)  alloc((size_t)N_LAYERS * 4096 * 1024 * 2);
    u16*   xw_bf   = (u16*)  alloc((size_t)N_LAYERS * XROWS * INTER * 2);
    u16*   dtw_bf  = (u16*)  alloc((size_t)N_LAYERS * INTER * DT_RANK * 2);
    u16*   outw_bf = (u16*)  alloc((size_t)N_LAYERS * D_MODEL * INTER * 2);
    float* h       = (float*)alloc((size_t)TOK * D_MODEL * 4);
    u16*   xn_bf   = (u16*)  alloc((size_t)TOK * D_MODEL * 2);
    u16*   proj_bf = (u16*)  alloc((size_t)TOK * 4096 * 2);
    u16*   u_bf    = (u16*)  alloc((size_t)TOK * INTER * 2);
    float* ssm     = (float*)alloc((size_t)TOK * XROWS * 4);
    // shared partials buffer (33.6MB): x_proj fp32 partials (16.8MB) and
    // out_proj bf16 partials (OSPL x 8.4MB = 33.6MB) - disjoint lifetimes.
    float* parts   = (float*)alloc((size_t)KSPL * TOK * XROWS * 4 > (size_t)OSPL * TOK * D_MODEL * 2
                                   ? (size_t)KSPL * TOK * XROWS * 4
                                   : (size_t)OSPL * TOK * D_MODEL * 2);
    u16*   partsbf = (u16*)parts;
    u16*   dtr_bf  = (u16*)  alloc((size_t)TOK * DT_RANK * 2);
    u16*   dt_bf   = (u16*)  alloc((size_t)TOK * INTER * 2);
    u16*   y_bf    = (u16*)  alloc((size_t)TOK * INTER * 2);
    float* cst     = (float*)alloc((size_t)B_SZ * GCH * INTER * D_STATE * 4);
    float* dts     = (float*)alloc((size_t)B_SZ * GCH * INTER * 4);
    int*   aflags  = (int*)  alloc(N_LAYERS * sizeof(int));
    (void)ws_size; (void)n_in; (void)in_sizes; (void)out_size;

    // weight conversion (merged) + A_log structure check
    {
        int total = INW_N + DTW_N + OUTW_N + XWP_N;
        cvtall_k<<<(total / 4 + 255) / 256, 256, 0, stream>>>(
            in_w, dt_w, out_w, x_w, inw_bf, dtw_bf, outw_bf, xw_bf);
        hipMemsetAsync(aflags, 0xFF, N_LAYERS * sizeof(int), stream);
        int na = N_LAYERS * INTER * D_STATE;
        achk_k<<<(na + 255) / 256, 256, 0, stream>>>(A_log, aflags);
    }

    for (int l = 0; l < N_LAYERS; ++l) {
        // 1. residual + rmsnorm -> xn_bf (and h update for l>=1)
        if (l == 0)
            rmsnorm_k<1><<<TOK, 256, 0, stream>>>(x, norm_w, xn_bf);
        else
            rmsnorm_res_k<1, 1><<<TOK, 256, 0, stream>>>(
                (l == 1) ? x : h, partsbf, norm_w + (size_t)l * D_MODEL, h, xn_bf);
        // 2. in_proj (256^2 8-phase, counted vmcnt + persistent frags)
        gemm256_k<<<dim3(16, 16), 512, 0, stream>>>(
            xn_bf, inw_bf + (size_t)l * 4096 * 1024, proj_bf, 1024, 4096);
        // 3. conv + silu (sliding window) -> u_bf
        conv_silu_k<<<TOK / 4, 256, 0, stream>>>(
            proj_bf, conv_w + (size_t)l * INTER * D_CONV, conv_b + (size_t)l * INTER, u_bf);
        // 4. x_proj split-K(8) -> fp32 partials
        gemm_bt<4, 1><<<dim3(KSPL, 32), 256, 0, stream>>>(
            u_bf, xw_bf + (size_t)l * XROWS * INTER, parts, nullptr,
            INTER / KSPL, INTER, XROWS, (size_t)TOK * XROWS);
        // 4b. reduce partials -> ssm fp32 + dtr bf16
        xred_k<<<(TOK * 32) / 256, 256, 0, stream>>>(parts, ssm, dtr_bf);
        // 5. dt_proj + softplus -> dt_bf [4096,2048]
        gemm_bt<2><<<dim3(16, 32), 256, 0, stream>>>(
            dtr_bf, dtw_bf + (size_t)l * INTER * DT_RANK, dt_bf,
            dt_b + (size_t)l * INTER, DT_RANK, DT_RANK, INTER, 0);
        // 6. chunked scan (+ skip + gate) -> y_bf
        scan1_k<<<dim3(INTER / 512, GCH, B_SZ), 256, 0, stream>>>(
            dt_bf, u_bf, ssm, A_log + (size_t)l * INTER * D_STATE, aflags + l, cst, dts);
        scan2_k<<<(B_SZ * INTER * 4) / 256, 256, 0, stream>>>(
            cst, dts, A_log + (size_t)l * INTER * D_STATE);
        scan3_k<<<dim3(INTER / 512, GCH, B_SZ), 256, 0, stream>>>(
            dt_bf, u_bf, ssm, proj_bf, A_log + (size_t)l * INTER * D_STATE,
            Dp + (size_t)l * INTER, aflags + l, cst, y_bf);
        // 7. out_proj split-K(4) -> bf16 partials (consumed by rmsnorm_res)
        gemm_bt<5, 8><<<dim3(OSPL * 8, 32), 256, 0, stream>>>(
            y_bf, outw_bf + (size_t)l * D_MODEL * INTER, partsbf, nullptr,
            INTER / OSPL, INTER, D_MODEL, (size_t)TOK * D_MODEL);
    }
    // final residual + rmsnorm -> d_out (fp32)
    rmsnorm_res_k<0, 0><<<TOK, 256, 0, stream>>>(
        h, partsbf, norm_f, nullptr, d_out);
}

// Round 15
// 857.887 us; speedup vs baseline: 1.0232x; 1.0232x over previous
//
#include <hip/hip_runtime.h>
#include <hip/hip_bf16.h>
#include <math.h>

#define D_MODEL 1024
#define N_LAYERS 4
#define INTER 2048
#define D_CONV 4
#define D_STATE 16
#define DT_RANK 64
#define B_SZ 4
#define SEQ 1024
#define TOK (B_SZ*SEQ)          // 4096 token rows
#define XROWS 128               // x_proj rows padded 96 -> 128
#define EPSV 1e-5f
#define GCH 64                  // scan chunks
#define TC (SEQ/GCH)            // 16 timesteps per chunk
#define KSPL 8                  // x_proj K-split factor
#define OSPL 2                  // out_proj K-split factor (fp32 partials)

typedef unsigned short u16;
typedef unsigned int u32;
typedef __attribute__((ext_vector_type(8))) short bf16x8;
typedef __attribute__((ext_vector_type(4))) short s16x4;
typedef __attribute__((ext_vector_type(4))) float f32x4;

__device__ __forceinline__ u16 f2b(float f) {
    union { float f; unsigned u; } v; v.f = f;
    unsigned r = v.u + 0x7fffu + ((v.u >> 16) & 1u);
    return (u16)(r >> 16);
}
__device__ __forceinline__ float b2f(u16 h) {
    union { unsigned u; float f; } v; v.u = ((unsigned)h) << 16;
    return v.f;
}
__device__ __forceinline__ float silu(float x) {
    return x / (1.f + __expf(-x));
}
__device__ __forceinline__ void gload16(const void* g, void* l) {
    __builtin_amdgcn_global_load_lds(
        (const __attribute__((address_space(1))) void*)g,
        (__attribute__((address_space(3))) void*)l, 16, 0, 0);
}

// ---------------------------------------------------------------------------
// in_proj GEMM: 256x256 8-phase, BK=64, counted vmcnt, XCD swizzle,
// persistent fragments (R12/R13 structure — plateau ~44us).
// ---------------------------------------------------------------------------
__global__ __launch_bounds__(512, 2)
void gemm256_k(const u16* __restrict__ A, const u16* __restrict__ B,
               u16* __restrict__ C, int K, int ldc)
{
    __shared__ u16 lds[2][2][256 * 64];
    const int tid  = threadIdx.x;
    const int lane = tid & 63;
    const int wid  = tid >> 6;
    const int wr   = wid >> 2;
    const int wc   = wid & 3;
    const int hwid = blockIdx.y * gridDim.x + blockIdx.x;     // 0..255
    const int work = (hwid & 7) * 32 + (hwid >> 3);           // XCD swizzle
    const int row0 = (work >> 4) * 256;
    const int col0 = (work & 15) * 256;
    const int r16   = lane & 15;
    const int khalf = lane >> 4;

    auto ld1 = [&](int buf, int k0, int l) {
        int op = l >> 2;
        int c  = tid + (l & 3) * 512;
        int r  = c >> 3;
        int ds = c & 7;
        int sc = (ds ^ (r & 7)) * 8;
        const u16* src = op ? &B[(size_t)(col0 + r) * K + k0 + sc]
                            : &A[(size_t)(row0 + r) * K + k0 + sc];
        gload16(src, &lds[buf][op][c * 8]);
    };
    // pairs: 0:{A0,A2} 1:{B0,B1} 2:{B2,B3} 3:{A1,A3}
    auto stage2 = [&](int buf, int k0, int pair) {
        if (pair == 0)      { ld1(buf, k0, 0); ld1(buf, k0, 2); }
        else if (pair == 1) { ld1(buf, k0, 4); ld1(buf, k0, 5); }
        else if (pair == 2) { ld1(buf, k0, 6); ld1(buf, k0, 7); }
        else                { ld1(buf, k0, 1); ld1(buf, k0, 3); }
    };
    auto rdA = [&](int buf, int mrow, int ks) -> bf16x8 {
        int row  = wr * 128 + mrow + r16;
        int phys = ((ks << 2) | khalf) ^ (row & 7);
        return *(const bf16x8*)&lds[buf][0][row * 64 + phys * 8];
    };
    auto rdB = [&](int buf, int nrow, int ks) -> bf16x8 {
        int row  = wc * 64 + nrow + r16;
        int phys = ((ks << 2) | khalf) ^ (row & 7);
        return *(const bf16x8*)&lds[buf][1][row * 64 + phys * 8];
    };

    f32x4 acc[8][4];
#pragma unroll
    for (int m = 0; m < 8; ++m)
#pragma unroll
        for (int n = 0; n < 4; ++n)
            acc[m][n] = (f32x4)0.f;

    bf16x8 afA[4][2], afB[4][2], b01[2][2], b23[2][2];

#define PHASE_MFMA(MH, NH, AF, BF) do {                                       \
    asm volatile("s_waitcnt lgkmcnt(0)" ::: "memory");                        \
    __builtin_amdgcn_sched_barrier(0);                                        \
    __builtin_amdgcn_s_setprio(1);                                            \
    _Pragma("unroll")                                                         \
    for (int ks = 0; ks < 2; ++ks)                                            \
        _Pragma("unroll")                                                     \
        for (int m = 0; m < 4; ++m)                                           \
            _Pragma("unroll")                                                 \
            for (int n = 0; n < 2; ++n)                                       \
                acc[(MH)*4+m][(NH)*2+n] =                                     \
                    __builtin_amdgcn_mfma_f32_16x16x32_bf16(                  \
                        AF[m][ks], BF[n][ks], acc[(MH)*4+m][(NH)*2+n],0,0,0); \
    __builtin_amdgcn_s_setprio(0);                                            \
} while (0)

    const int nt = K >> 6;
    stage2(0, 0, 0); stage2(0, 0, 1); stage2(0, 0, 3); stage2(0, 0, 2);
    asm volatile("s_waitcnt vmcnt(4)" ::: "memory");
    __builtin_amdgcn_s_barrier();

    for (int j = 0; j < nt; ++j) {
        const int buf = j & 1;
        const int nb  = buf ^ 1;
        const int k1  = (j + 1) << 6;
        const bool pf = (j + 1 < nt);
        // phase 0: quadrant (0,0); read afA + B01; issue p0^{j+1}
        if (pf) stage2(nb, k1, 0);
#pragma unroll
        for (int m = 0; m < 4; ++m) {
            afA[m][0] = rdA(buf, m * 16, 0); afA[m][1] = rdA(buf, m * 16, 1);
        }
#pragma unroll
        for (int n = 0; n < 2; ++n) {
            b01[n][0] = rdB(buf, n * 16, 0); b01[n][1] = rdB(buf, n * 16, 1);
        }
        __builtin_amdgcn_s_barrier();
        PHASE_MFMA(0, 0, afA, b01);
        if (pf) { asm volatile("s_waitcnt vmcnt(4)" ::: "memory"); }  // p3^j
        else    { asm volatile("s_waitcnt vmcnt(2)" ::: "memory"); }
        __builtin_amdgcn_s_barrier();
        // phase 1: quadrant (1,0); read afB; issue p1^{j+1}
        if (pf) stage2(nb, k1, 1);
#pragma unroll
        for (int m = 0; m < 4; ++m) {
            afB[m][0] = rdA(buf, 64 + m * 16, 0); afB[m][1] = rdA(buf, 64 + m * 16, 1);
        }
        __builtin_amdgcn_s_barrier();
        PHASE_MFMA(1, 0, afB, b01);
        if (pf) { asm volatile("s_waitcnt vmcnt(4)" ::: "memory"); }  // p2^j
        else    { asm volatile("s_waitcnt vmcnt(0)" ::: "memory"); }
        __builtin_amdgcn_s_barrier();
        // phase 2: quadrant (1,1); read B23; issue p3^{j+1}
        if (pf) stage2(nb, k1, 3);
#pragma unroll
        for (int n = 0; n < 2; ++n) {
            b23[n][0] = rdB(buf, 32 + n * 16, 0); b23[n][1] = rdB(buf, 32 + n * 16, 1);
        }
        __builtin_amdgcn_s_barrier();
        PHASE_MFMA(1, 1, afB, b23);
        __builtin_amdgcn_s_barrier();
        // phase 3: quadrant (0,1); no reads; issue p2^{j+1}
        if (pf) stage2(nb, k1, 2);
        PHASE_MFMA(0, 1, afA, b23);
        if (pf) { asm volatile("s_waitcnt vmcnt(4)" ::: "memory"); }  // p0,p1
        __builtin_amdgcn_s_barrier();
    }
#undef PHASE_MFMA

    const int orow = row0 + wr * 128;
    const int ocol = col0 + wc * 64;
#pragma unroll
    for (int am = 0; am < 8; ++am)
#pragma unroll
        for (int an = 0; an < 4; ++an)
#pragma unroll
            for (int r = 0; r < 4; ++r) {
                int rr = orow + am * 16 + khalf * 4 + r;
                int cc = ocol + an * 16 + r16;
                C[(size_t)rr * ldc + cc] = f2b(acc[am][an][r]);
            }
}

// ---------------------------------------------------------------------------
// 128x128 GEMM: 3-buffer pipeline, swizzled.
// EPI: 0 = fp32, 2 = softplus(acc+aux[col])->bf16,
//      4 = split-K partial fp32 (part = blockIdx.x / NPX, col-tile = % NPX)
// ---------------------------------------------------------------------------
template<int EPI, int NPX = 1>
__global__ __launch_bounds__(256)
void gemm_bt(const u16* __restrict__ A, const u16* __restrict__ B,
             void* __restrict__ C, const float* __restrict__ aux,
             int K, int lda, int ldc, size_t pstride)
{
    __shared__ u16 As[3][128 * 32];
    __shared__ u16 Bs[3][128 * 32];
    const int tid  = threadIdx.x;
    const int lane = tid & 63;
    const int w    = tid >> 6;
    const int wr   = w >> 1, wc = w & 1;
    const int row0 = blockIdx.y * 128;
    int col0 = blockIdx.x * 128;
    if (EPI == 4) {
        int part = blockIdx.x / NPX;
        col0 = (blockIdx.x % NPX) * 128;
        A += (size_t)part * K;
        B += (size_t)part * K;
        C = (void*)((float*)C + (size_t)part * pstride);
    }
    const int r16   = lane & 15;
    const int khalf = lane >> 4;
    const int kslot = khalf ^ ((r16 >> 1) & 3);

    auto stage = [&](int buf, int k0) {
#pragma unroll
        for (int c = 0; c < 2; ++c) {
            int chunk = tid + c * 256;
            int r  = chunk >> 2;
            int j  = chunk & 3;
            int k8 = (j ^ ((r >> 1) & 3)) * 8;
            gload16(&A[(size_t)(row0 + r) * lda + k0 + k8], &As[buf][chunk * 8]);
            gload16(&B[(size_t)(col0 + r) * lda + k0 + k8], &Bs[buf][chunk * 8]);
        }
    };

    f32x4 acc[4][4];
#pragma unroll
    for (int m = 0; m < 4; ++m)
#pragma unroll
        for (int n = 0; n < 4; ++n)
            acc[m][n] = (f32x4)0.f;

    const int nt = K >> 5;
    stage(0, 0);
    if (nt > 1) stage(1, 32);

    int cur = 0, sb = 2;
    for (int t = 0; t < nt; ++t) {
        if (t + 2 < nt) {
            stage(sb, (t + 2) << 5);
            asm volatile("s_waitcnt vmcnt(8)" ::: "memory");
        } else if (t + 1 < nt) {
            asm volatile("s_waitcnt vmcnt(4)" ::: "memory");
        } else {
            asm volatile("s_waitcnt vmcnt(0)" ::: "memory");
        }
        __builtin_amdgcn_s_barrier();

        bf16x8 af[4], bfr[4];
#pragma unroll
        for (int m = 0; m < 4; ++m)
            af[m]  = *(const bf16x8*)&As[cur][(wr * 64 + m * 16 + r16) * 32 + kslot * 8];
#pragma unroll
        for (int n = 0; n < 4; ++n)
            bfr[n] = *(const bf16x8*)&Bs[cur][(wc * 64 + n * 16 + r16) * 32 + kslot * 8];
#pragma unroll
        for (int m = 0; m < 4; ++m)
#pragma unroll
            for (int n = 0; n < 4; ++n)
                acc[m][n] = __builtin_amdgcn_mfma_f32_16x16x32_bf16(
                    af[m], bfr[n], acc[m][n], 0, 0, 0);

        __builtin_amdgcn_sched_barrier(0);
        asm volatile("s_waitcnt lgkmcnt(0)" ::: "memory");
        __builtin_amdgcn_s_barrier();
        cur = (cur == 2) ? 0 : cur + 1;
        sb  = (sb  == 2) ? 0 : sb  + 1;
    }

    const int orow = row0 + wr * 64;
    const int ocol = col0 + wc * 64;
#pragma unroll
    for (int m = 0; m < 4; ++m)
#pragma unroll
        for (int n = 0; n < 4; ++n) {
#pragma unroll
            for (int r = 0; r < 4; ++r) {
                int rr = orow + m * 16 + khalf * 4 + r;
                int cc = ocol + n * 16 + r16;
                float v = acc[m][n][r];
                size_t o = (size_t)rr * ldc + cc;
                if (EPI == 0 || EPI == 4) {
                    ((float*)C)[o] = v;
                } else if (EPI == 2) {
                    float x = v + aux[cc];
                    float sp = (x > 20.f) ? x : log1pf(__expf(x));
                    ((u16*)C)[o] = f2b(sp);
                }
            }
        }
}

// ---------------------------------------------------------------------------
// x_proj split-K reduce: ssm = sum of KSPL fp32 partials + bf16 dt-rank cols.
// ---------------------------------------------------------------------------
__global__ __launch_bounds__(256)
void xred_k(const float* __restrict__ part, float* __restrict__ ssm,
            u16* __restrict__ dtr)
{
    int idx = blockIdx.x * 256 + threadIdx.x;
    int row = idx >> 5;
    int col = (idx & 31) * 4;
    size_t o = (size_t)row * XROWS + col;
    const size_t stride = (size_t)TOK * XROWS;
    f32x4 v = *(const f32x4*)&part[o];
#pragma unroll
    for (int p = 1; p < KSPL; ++p)
        v += *(const f32x4*)&part[o + p * stride];
    *(f32x4*)&ssm[o] = v;
    if (col < DT_RANK) {
        s16x4 d;
#pragma unroll
        for (int j = 0; j < 4; ++j) d[j] = (short)f2b(v[j]);
        *(s16x4*)&dtr[(size_t)row * DT_RANK + col] = d;
    }
}

// ---------------------------------------------------------------------------
// RMSNorm (plain): rows of 1024 fp32 -> bf16/fp32.
// ---------------------------------------------------------------------------
template<int OUTBF>
__global__ __launch_bounds__(256)
void rmsnorm_k(const float* __restrict__ in, const float* __restrict__ w,
               void* __restrict__ out)
{
    __shared__ float red[4];
    const int row = blockIdx.x;
    const int tid = threadIdx.x;
    const float* r = in + (size_t)row * D_MODEL;
    f32x4 v = *(const f32x4*)&r[tid * 4];
    float ss = v[0]*v[0] + v[1]*v[1] + v[2]*v[2] + v[3]*v[3];
#pragma unroll
    for (int m = 32; m >= 1; m >>= 1) ss += __shfl_xor(ss, m, 64);
    if ((tid & 63) == 0) red[tid >> 6] = ss;
    __syncthreads();
    if (tid == 0) {
        float s = red[0] + red[1] + red[2] + red[3];
        red[0] = rsqrtf(s / (float)D_MODEL + EPSV);
    }
    __syncthreads();
    float sc = red[0];
    if (OUTBF) {
        u16* o = (u16*)out + (size_t)row * D_MODEL + tid * 4;
#pragma unroll
        for (int j = 0; j < 4; ++j) o[j] = f2b(v[j] * sc * w[tid * 4 + j]);
    } else {
        float* o = (float*)out + (size_t)row * D_MODEL + tid * 4;
#pragma unroll
        for (int j = 0; j < 4; ++j) o[j] = v[j] * sc * w[tid * 4 + j];
    }
}

// ---------------------------------------------------------------------------
// Fused residual + RMSNorm: hn = hin + p0 + p1 (out_proj fp32 partials);
// optionally write hn to hout; write normalized output (bf16 or fp32).
// ---------------------------------------------------------------------------
template<int OUTBF, int WRITEH>
__global__ __launch_bounds__(256)
void rmsnorm_res_k(const float* __restrict__ hin, const float* __restrict__ p,
                   const float* __restrict__ w, float* __restrict__ hout,
                   void* __restrict__ out)
{
    __shared__ float red[4];
    const int row = blockIdx.x;
    const int tid = threadIdx.x;
    const size_t o4 = (size_t)row * D_MODEL + tid * 4;
    f32x4 v  = *(const f32x4*)&hin[o4];
    f32x4 p0 = *(const f32x4*)&p[o4];
    f32x4 p1 = *(const f32x4*)&p[(size_t)TOK * D_MODEL + o4];
    v += p0 + p1;
    if (WRITEH) *(f32x4*)&hout[o4] = v;
    float ss = v[0]*v[0] + v[1]*v[1] + v[2]*v[2] + v[3]*v[3];
#pragma unroll
    for (int m = 32; m >= 1; m >>= 1) ss += __shfl_xor(ss, m, 64);
    if ((tid & 63) == 0) red[tid >> 6] = ss;
    __syncthreads();
    if (tid == 0) {
        float s = red[0] + red[1] + red[2] + red[3];
        red[0] = rsqrtf(s / (float)D_MODEL + EPSV);
    }
    __syncthreads();
    float sc = red[0];
    if (OUTBF) {
        u16* o = (u16*)out + o4;
#pragma unroll
        for (int j = 0; j < 4; ++j) o[j] = f2b(v[j] * sc * w[tid * 4 + j]);
    } else {
        float* o = (float*)out + o4;
#pragma unroll
        for (int j = 0; j < 4; ++j) o[j] = v[j] * sc * w[tid * 4 + j];
    }
}

// ---------------------------------------------------------------------------
// Depthwise causal conv + bias + SiLU, sliding window (4 tokens/block).
// ---------------------------------------------------------------------------
__global__ __launch_bounds__(256)
void conv_silu_k(const u16* __restrict__ projbf, const float* __restrict__ w,
                 const float* __restrict__ bias, u16* __restrict__ ubf)
{
    const int tok0 = blockIdx.x * 4;
    const int t0   = tok0 & (SEQ - 1);
    const int i0   = threadIdx.x * 8;
    float hv[7][8];
#pragma unroll
    for (int m = 0; m < 7; ++m) {
        int tt = t0 - 3 + m;
        if (tt >= 0) {
            bf16x8 v = *(const bf16x8*)&projbf[(size_t)(tok0 - 3 + m) * 4096 + i0];
#pragma unroll
            for (int j = 0; j < 8; ++j) hv[m][j] = b2f((u16)v[j]);
        } else {
#pragma unroll
            for (int j = 0; j < 8; ++j) hv[m][j] = 0.f;
        }
    }
    f32x4 wv[8];
#pragma unroll
    for (int j = 0; j < 8; ++j)
        wv[j] = *(const f32x4*)&w[(i0 + j) * 4];
    float bs[8];
    {
        f32x4 b0 = *(const f32x4*)&bias[i0];
        f32x4 b1 = *(const f32x4*)&bias[i0 + 4];
#pragma unroll
        for (int j = 0; j < 4; ++j) { bs[j] = b0[j]; bs[j + 4] = b1[j]; }
    }
#pragma unroll
    for (int q = 0; q < 4; ++q) {
        bf16x8 o;
#pragma unroll
        for (int j = 0; j < 8; ++j) {
            float acc = bs[j];
#pragma unroll
            for (int k = 0; k < 4; ++k)
                acc += hv[q + k][j] * wv[j][k];
            o[j] = (short)f2b(silu(acc));
        }
        *(bf16x8*)&ubf[(size_t)(tok0 + q) * INTER + i0] = o;
    }
}

// ---------------------------------------------------------------------------
// A_log structure check (fast-path guard).
// ---------------------------------------------------------------------------
__global__ __launch_bounds__(256)
void achk_k(const float* __restrict__ Alog, int* __restrict__ flags)
{
    int idx = blockIdx.x * 256 + threadIdx.x;
    if (idx >= N_LAYERS * INTER * D_STATE) return;
    int l = idx / (INTER * D_STATE);
    int n = idx & (D_STATE - 1);
    float ref = logf((float)(n + 1));
    if (fabsf(Alog[idx] - ref) > 1e-4f) atomicAnd(&flags[l], 0);
}

// ---------------------------------------------------------------------------
// Chunked selective scan, 2 channels per thread (ILP x2, packed u32 loads).
// Fast path: decay exp(dt*a_n) == w^(n+1), w = exp(-dt).
// ---------------------------------------------------------------------------
#define POWCH(W, p) \
    float p##2=(W)*(W), p##3=p##2*(W), p##4=p##2*p##2, p##5=p##4*(W),        \
          p##6=p##4*p##2, p##7=p##4*p##3, p##8=p##4*p##4, p##9=p##8*(W),     \
          p##10=p##8*p##2, p##11=p##8*p##3, p##12=p##8*p##4, p##13=p##8*p##5,\
          p##14=p##8*p##6, p##15=p##8*p##7, p##16=p##8*p##8;

#define SUPD(S, B, du, w1) \
    S[0]=w1*S[0]+du*B[0][0];   S[1]=w1##2*S[1]+du*B[0][1];                   \
    S[2]=w1##3*S[2]+du*B[0][2];  S[3]=w1##4*S[3]+du*B[0][3];                 \
    S[4]=w1##5*S[4]+du*B[1][0];  S[5]=w1##6*S[5]+du*B[1][1];                 \
    S[6]=w1##7*S[6]+du*B[1][2];  S[7]=w1##8*S[7]+du*B[1][3];                 \
    S[8]=w1##9*S[8]+du*B[2][0];  S[9]=w1##10*S[9]+du*B[2][1];                \
    S[10]=w1##11*S[10]+du*B[2][2]; S[11]=w1##12*S[11]+du*B[2][3];            \
    S[12]=w1##13*S[12]+du*B[3][0]; S[13]=w1##14*S[13]+du*B[3][1];            \
    S[14]=w1##15*S[14]+du*B[3][2]; S[15]=w1##16*S[15]+du*B[3][3];

#define YDOT(S, Cv) \
    (S[0]*Cv[0][0]+S[1]*Cv[0][1]+S[2]*Cv[0][2]+S[3]*Cv[0][3]                 \
    +S[4]*Cv[1][0]+S[5]*Cv[1][1]+S[6]*Cv[1][2]+S[7]*Cv[1][3]                 \
    +S[8]*Cv[2][0]+S[9]*Cv[2][1]+S[10]*Cv[2][2]+S[11]*Cv[2][3]               \
    +S[12]*Cv[3][0]+S[13]*Cv[3][1]+S[14]*Cv[3][2]+S[15]*Cv[3][3])

__global__ __launch_bounds__(256)
void scan1_k(const u16* __restrict__ dtbf, const u16* __restrict__ ubf,
             const float* __restrict__ ssm, const float* __restrict__ Alog,
             const int* __restrict__ flag,
             float* __restrict__ cst, float* __restrict__ dts)
{
    __shared__ float Bsh[TC][D_STATE];
    const int tid = threadIdx.x;
    const int i2  = blockIdx.x * 256 + tid;     // channel pair index
    const int c0  = i2 * 2;
    const int g   = blockIdx.y;
    const int b   = blockIdx.z;
    const int t0  = g * TC;
    {
        int t = tid >> 4, n = tid & 15;        // TC*16 = 256
        Bsh[t][n] = ssm[(size_t)(b * SEQ + t0 + t) * XROWS + DT_RANK + n];
    }
    __syncthreads();

    float s0[D_STATE], s1[D_STATE];
#pragma unroll
    for (int n = 0; n < D_STATE; ++n) { s0[n] = 0.f; s1[n] = 0.f; }
    float ds0 = 0.f, ds1 = 0.f;

    const u32* dtp = (const u32*)dtbf + ((size_t)(b * SEQ + t0) * INTER >> 1) + i2;
    const u32* up  = (const u32*)ubf  + ((size_t)(b * SEQ + t0) * INTER >> 1) + i2;

    if (flag[0]) {
#pragma unroll
        for (int t = 0; t < TC; ++t) {
            u32 dp = dtp[(size_t)t * (INTER / 2)];
            u32 uq = up[(size_t)t * (INTER / 2)];
            float dta = b2f((u16)dp), dtb = b2f((u16)(dp >> 16));
            float ua  = b2f((u16)uq), ub  = b2f((u16)(uq >> 16));
            float dua = dta * ua, dub = dtb * ub;
            ds0 += dta; ds1 += dtb;
            float wa = __expf(-dta), wb = __expf(-dtb);
            POWCH(wa, wa) POWCH(wb, wb)
            f32x4 Bq[4];
#pragma unroll
            for (int q = 0; q < 4; ++q) Bq[q] = *(const f32x4*)&Bsh[t][q * 4];
            SUPD(s0, Bq, dua, wa)
            SUPD(s1, Bq, dub, wb)
        }
    } else {
        float a0[D_STATE], a1[D_STATE];
#pragma unroll
        for (int n = 0; n < D_STATE; ++n) {
            a0[n] = -__expf(Alog[(size_t)c0 * D_STATE + n]);
            a1[n] = -__expf(Alog[(size_t)(c0 + 1) * D_STATE + n]);
        }
        for (int t = 0; t < TC; ++t) {
            u32 dp = dtp[(size_t)t * (INTER / 2)];
            u32 uq = up[(size_t)t * (INTER / 2)];
            float dta = b2f((u16)dp), dtb = b2f((u16)(dp >> 16));
            float ua  = b2f((u16)uq), ub  = b2f((u16)(uq >> 16));
            float dua = dta * ua, dub = dtb * ub;
            ds0 += dta; ds1 += dtb;
#pragma unroll
            for (int n = 0; n < D_STATE; ++n) {
                float Bn = Bsh[t][n];
                s0[n] = __expf(dta * a0[n]) * s0[n] + dua * Bn;
                s1[n] = __expf(dtb * a1[n]) * s1[n] + dub * Bn;
            }
        }
    }
    size_t o = ((size_t)(b * GCH + g) * INTER + c0) * D_STATE;
#pragma unroll
    for (int n = 0; n < D_STATE; n += 4) {
        f32x4 v0 = { s0[n], s0[n+1], s0[n+2], s0[n+3] };
        f32x4 v1 = { s1[n], s1[n+1], s1[n+2], s1[n+3] };
        *(f32x4*)&cst[o + n] = v0;
        *(f32x4*)&cst[o + D_STATE + n] = v1;
    }
    size_t od = (size_t)(b * GCH + g) * INTER + c0;
    dts[od] = ds0; dts[od + 1] = ds1;
}

// in-place: cst local chunk-end -> chunk-START states.
__global__ __launch_bounds__(256)
void scan2_k(float* __restrict__ cst, const float* __restrict__ dts,
             const float* __restrict__ Alog)
{
    int idx = blockIdx.x * 256 + threadIdx.x;
    int sub = idx & 3;
    int i   = (idx >> 2) & (INTER - 1);
    int b   = idx >> 13;
    int n0  = sub * 4;
    float a[4];
#pragma unroll
    for (int n = 0; n < 4; ++n)
        a[n] = -__expf(Alog[(size_t)i * D_STATE + n0 + n]);
    f32x4 s = (f32x4)0.f;
    for (int g = 0; g < GCH; ++g) {
        size_t o = ((size_t)(b * GCH + g) * INTER + i) * D_STATE + n0;
        f32x4 tmp = *(const f32x4*)&cst[o];
        *(f32x4*)&cst[o] = s;
        float d = dts[(size_t)(b * GCH + g) * INTER + i];
#pragma unroll
        for (int n = 0; n < 4; ++n)
            s[n] = __expf(a[n] * d) * s[n] + tmp[n];
    }
}

__global__ __launch_bounds__(256)
void scan3_k(const u16* __restrict__ dtbf, const u16* __restrict__ ubf,
             const float* __restrict__ ssm, const u16* __restrict__ projbf,
             const float* __restrict__ Alog, const float* __restrict__ Dp,
             const int* __restrict__ flag,
             const float* __restrict__ sst, u16* __restrict__ ybf)
{
    __shared__ float Bsh[TC][D_STATE];
    __shared__ float Csh[TC][D_STATE];
    const int tid = threadIdx.x;
    const int i2  = blockIdx.x * 256 + tid;
    const int c0  = i2 * 2;
    const int g   = blockIdx.y;
    const int b   = blockIdx.z;
    const int t0  = g * TC;
    {
        int t = tid >> 4, n = tid & 15;
        size_t row = (size_t)(b * SEQ + t0 + t) * XROWS;
        Bsh[t][n] = ssm[row + DT_RANK + n];
        Csh[t][n] = ssm[row + DT_RANK + D_STATE + n];
    }
    __syncthreads();

    const float Da = Dp[c0], Db = Dp[c0 + 1];
    float s0[D_STATE], s1[D_STATE];
    size_t so = ((size_t)(b * GCH + g) * INTER + c0) * D_STATE;
#pragma unroll
    for (int n = 0; n < D_STATE; n += 4) {
        f32x4 v0 = *(const f32x4*)&sst[so + n];
        f32x4 v1 = *(const f32x4*)&sst[so + D_STATE + n];
        s0[n] = v0[0]; s0[n+1] = v0[1]; s0[n+2] = v0[2]; s0[n+3] = v0[3];
        s1[n] = v1[0]; s1[n+1] = v1[1]; s1[n+2] = v1[2]; s1[n+3] = v1[3];
    }

    const u32* dtp = (const u32*)dtbf + ((size_t)(b * SEQ + t0) * INTER >> 1) + i2;
    const u32* up  = (const u32*)ubf  + ((size_t)(b * SEQ + t0) * INTER >> 1) + i2;
    const u32* gp  = (const u32*)projbf + (((size_t)(b * SEQ + t0) * 4096 + INTER) >> 1) + i2;
    u32*       yp  = (u32*)ybf + ((size_t)(b * SEQ + t0) * INTER >> 1) + i2;

    if (flag[0]) {
#pragma unroll
        for (int t = 0; t < TC; ++t) {
            u32 dp = dtp[(size_t)t * (INTER / 2)];
            u32 uq = up[(size_t)t * (INTER / 2)];
            u32 gq = gp[(size_t)t * (4096 / 2)];
            float dta = b2f((u16)dp), dtb = b2f((u16)(dp >> 16));
            float ua  = b2f((u16)uq), ub  = b2f((u16)(uq >> 16));
            float ga  = b2f((u16)gq), gb  = b2f((u16)(gq >> 16));
            float dua = dta * ua, dub = dtb * ub;
            float wa = __expf(-dta), wb = __expf(-dtb);
            POWCH(wa, wa) POWCH(wb, wb)
            f32x4 Bq[4], Cq[4];
#pragma unroll
            for (int q = 0; q < 4; ++q) {
                Bq[q] = *(const f32x4*)&Bsh[t][q * 4];
                Cq[q] = *(const f32x4*)&Csh[t][q * 4];
            }
            SUPD(s0, Bq, dua, wa)
            SUPD(s1, Bq, dub, wb)
            float y0 = YDOT(s0, Cq);
            float y1 = YDOT(s1, Cq);
            y0 = (y0 + Da * ua) * silu(ga);
            y1 = (y1 + Db * ub) * silu(gb);
            yp[(size_t)t * (INTER / 2)] = (u32)f2b(y0) | ((u32)f2b(y1) << 16);
        }
    } else {
        float a0[D_STATE], a1[D_STATE];
#pragma unroll
        for (int n = 0; n < D_STATE; ++n) {
            a0[n] = -__expf(Alog[(size_t)c0 * D_STATE + n]);
            a1[n] = -__expf(Alog[(size_t)(c0 + 1) * D_STATE + n]);
        }
        for (int t = 0; t < TC; ++t) {
            u32 dp = dtp[(size_t)t * (INTER / 2)];
            u32 uq = up[(size_t)t * (INTER / 2)];
            u32 gq = gp[(size_t)t * (4096 / 2)];
            float dta = b2f((u16)dp), dtb = b2f((u16)(dp >> 16));
            float ua  = b2f((u16)uq), ub  = b2f((u16)(uq >> 16));
            float ga  = b2f((u16)gq), gb  = b2f((u16)(gq >> 16));
            float dua = dta * ua, dub = dtb * ub;
            float y0 = 0.f, y1 = 0.f;
#pragma unroll
            for (int n = 0; n < D_STATE; ++n) {
                float Bn = Bsh[t][n], Cn = Csh[t][n];
                s0[n] = __expf(dta * a0[n]) * s0[n] + dua * Bn;
                s1[n] = __expf(dtb * a1[n]) * s1[n] + dub * Bn;
                y0 += s0[n] * Cn; y1 += s1[n] * Cn;
            }
            y0 = (y0 + Da * ua) * silu(ga);
            y1 = (y1 + Db * ub) * silu(gb);
            yp[(size_t)t * (INTER / 2)] = (u32)f2b(y0) | ((u32)f2b(y1) << 16);
        }
    }
}

// ---------------------------------------------------------------------------
// Merged weight conversion fp32 -> bf16 (inw | dtw | outw | xw-pad).
// ---------------------------------------------------------------------------
#define INW_N  (N_LAYERS * 4096 * 1024)
#define DTW_N  (N_LAYERS * INTER * DT_RANK)
#define OUTW_N (N_LAYERS * D_MODEL * INTER)
#define XWP_N  (N_LAYERS * XROWS * INTER)
__global__ __launch_bounds__(256)
void cvtall_k(const float* __restrict__ in_w, const float* __restrict__ dt_w,
              const float* __restrict__ out_w, const float* __restrict__ xw,
              u16* __restrict__ inw_bf, u16* __restrict__ dtw_bf,
              u16* __restrict__ outw_bf, u16* __restrict__ xw_bf)
{
    int idx = (blockIdx.x * 256 + threadIdx.x) * 4;
    const float* src;
    u16* dst;
    int i;
    if (idx < INW_N) {
        src = in_w; dst = inw_bf; i = idx;
    } else if (idx < INW_N + DTW_N) {
        src = dt_w; dst = dtw_bf; i = idx - INW_N;
    } else if (idx < INW_N + DTW_N + OUTW_N) {
        src = out_w; dst = outw_bf; i = idx - INW_N - DTW_N;
    } else {
        i = idx - INW_N - DTW_N - OUTW_N;
        if (i >= XWP_N) return;
        int l = i / (XROWS * INTER);
        int r = (i >> 11) & (XROWS - 1);
        int c = i & (INTER - 1);
        s16x4 d;
        if (r < 96) {
            f32x4 v = *(const f32x4*)&xw[((size_t)l * 96 + r) * INTER + c];
#pragma unroll
            for (int j = 0; j < 4; ++j) d[j] = (short)f2b(v[j]);
        } else {
            d = (s16x4)0;
        }
        *(s16x4*)&xw_bf[i] = d;
        return;
    }
    f32x4 v = *(const f32x4*)&src[i];
    s16x4 d;
#pragma unroll
    for (int j = 0; j < 4; ++j) d[j] = (short)f2b(v[j]);
    *(s16x4*)&dst[i] = d;
}

// ---------------------------------------------------------------------------
extern "C" void kernel_launch(void* const* d_in, const int* in_sizes, int n_in,
                              void* d_out, int out_size, void* d_ws, size_t ws_size,
                              hipStream_t stream)
{
    const float* x      = (const float*)d_in[0];
    const float* in_w   = (const float*)d_in[1];
    const float* conv_w = (const float*)d_in[2];
    const float* conv_b = (const float*)d_in[3];
    const float* x_w    = (const float*)d_in[4];
    const float* dt_w   = (const float*)d_in[5];
    const float* dt_b   = (const float*)d_in[6];
    const float* A_log  = (const float*)d_in[7];
    const float* Dp     = (const float*)d_in[8];
    const float* out_w  = (const float*)d_in[9];
    const float* norm_w = (const float*)d_in[10];
    const float* norm_f = (const float*)d_in[11];

    char* ws = (char*)d_ws;
    size_t off = 0;
    auto alloc = [&](size_t bytes) { char* p = ws + off; off += (bytes + 255) & ~(size_t)255; return p; };

    u16*   inw_bf  = (u16*)  alloc((size_t)N_LAYERS * 4096 * 1024 * 2);
    u16*   xw_bf   = (u16*)  alloc((size_t)N_LAYERS * XROWS * INTER * 2);
    u16*   dtw_bf  = (u16*)  alloc((size_t)N_LAYERS * INTER * DT_RANK * 2);
    u16*   outw_bf = (u16*)  alloc((size_t)N_LAYERS * D_MODEL * INTER * 2);
    float* h       = (float*)alloc((size_t)TOK * D_MODEL * 4);
    u16*   xn_bf   = (u16*)  alloc((size_t)TOK * D_MODEL * 2);
    u16*   proj_bf = (u16*)  alloc((size_t)TOK * 4096 * 2);
    u16*   u_bf    = (u16*)  alloc((size_t)TOK * INTER * 2);
    float* ssm     = (float*)alloc((size_t)TOK * XROWS * 4);
    // shared partials buffer (33.6MB): x_proj fp32 partials (16.8MB) and
    // out_proj fp32 partials (OSPL x 16.8MB = 33.6MB) - disjoint lifetimes.
    float* parts   = (float*)alloc((size_t)OSPL * TOK * D_MODEL * 4);
    u16*   dtr_bf  = (u16*)  alloc((size_t)TOK * DT_RANK * 2);
    u16*   dt_bf   = (u16*)  alloc((size_t)TOK * INTER * 2);
    u16*   y_bf    = (u16*)  alloc((size_t)TOK * INTER * 2);
    float* cst     = (float*)alloc((size_t)B_SZ * GCH * INTER * D_STATE * 4);
    float* dts     = (float*)alloc((size_t)B_SZ * GCH * INTER * 4);
    int*   aflags  = (int*)  alloc(N_LAYERS * sizeof(int));
    (void)ws_size; (void)n_in; (void)in_sizes; (void)out_size;

    // weight conversion (merged) + A_log structure check
    {
        int total = INW_N + DTW_N + OUTW_N + XWP_N;
        cvtall_k<<<(total / 4 + 255) / 256, 256, 0, stream>>>(
            in_w, dt_w, out_w, x_w, inw_bf, dtw_bf, outw_bf, xw_bf);
        hipMemsetAsync(aflags, 0xFF, N_LAYERS * sizeof(int), stream);
        int na = N_LAYERS * INTER * D_STATE;
        achk_k<<<(na + 255) / 256, 256, 0, stream>>>(A_log, aflags);
    }

    for (int l = 0; l < N_LAYERS; ++l) {
        // 1. residual + rmsnorm -> xn_bf (and h update for l>=1)
        if (l == 0)
            rmsnorm_k<1><<<TOK, 256, 0, stream>>>(x, norm_w, xn_bf);
        else
            rmsnorm_res_k<1, 1><<<TOK, 256, 0, stream>>>(
                (l == 1) ? x : h, parts, norm_w + (size_t)l * D_MODEL, h, xn_bf);
        // 2. in_proj (256^2 8-phase, counted vmcnt + persistent frags)
        gemm256_k<<<dim3(16, 16), 512, 0, stream>>>(
            xn_bf, inw_bf + (size_t)l * 4096 * 1024, proj_bf, 1024, 4096);
        // 3. conv + silu (sliding window) -> u_bf
        conv_silu_k<<<TOK / 4, 256, 0, stream>>>(
            proj_bf, conv_w + (size_t)l * INTER * D_CONV, conv_b + (size_t)l * INTER, u_bf);
        // 4. x_proj split-K(8) -> fp32 partials
        gemm_bt<4, 1><<<dim3(KSPL, 32), 256, 0, stream>>>(
            u_bf, xw_bf + (size_t)l * XROWS * INTER, parts, nullptr,
            INTER / KSPL, INTER, XROWS, (size_t)TOK * XROWS);
        // 4b. reduce partials -> ssm fp32 + dtr bf16
        xred_k<<<(TOK * 32) / 256, 256, 0, stream>>>(parts, ssm, dtr_bf);
        // 5. dt_proj + softplus -> dt_bf [4096,2048]
        gemm_bt<2><<<dim3(16, 32), 256, 0, stream>>>(
            dtr_bf, dtw_bf + (size_t)l * INTER * DT_RANK, dt_bf,
            dt_b + (size_t)l * INTER, DT_RANK, DT_RANK, INTER, 0);
        // 6. chunked scan (+ skip + gate) -> y_bf
        scan1_k<<<dim3(INTER / 512, GCH, B_SZ), 256, 0, stream>>>(
            dt_bf, u_bf, ssm, A_log + (size_t)l * INTER * D_STATE, aflags + l, cst, dts);
        scan2_k<<<(B_SZ * INTER * 4) / 256, 256, 0, stream>>>(
            cst, dts, A_log + (size_t)l * INTER * D_STATE);
        scan3_k<<<dim3(INTER / 512, GCH, B_SZ), 256, 0, stream>>>(
            dt_bf, u_bf, ssm, proj_bf, A_log + (size_t)l * INTER * D_STATE,
            Dp + (size_t)l * INTER, aflags + l, cst, y_bf);
        // 7. out_proj split-K(2) -> fp32 partials (consumed by rmsnorm_res)
        gemm_bt<4, 8><<<dim3(OSPL * 8, 32), 256, 0, stream>>>(
            y_bf, outw_bf + (size_t)l * D_MODEL * INTER, parts, nullptr,
            INTER / OSPL, INTER, D_MODEL, (size_t)TOK * D_MODEL);
    }
    // final residual + rmsnorm -> d_out (fp32)
    rmsnorm_res_k<0, 0><<<TOK, 256, 0, stream>>>(
        h, parts, norm_f, nullptr, d_out);
}

// Round 16
// 847.044 us; speedup vs baseline: 1.0362x; 1.0128x over previous
//
#include <hip/hip_runtime.h>
#include <hip/hip_bf16.h>
#include <math.h>

#define D_MODEL 1024
#define N_LAYERS 4
#define INTER 2048
#define D_CONV 4
#define D_STATE 16
#define DT_RANK 64
#define B_SZ 4
#define SEQ 1024
#define TOK (B_SZ*SEQ)          // 4096 token rows
#define XROWS 128               // x_proj rows padded 96 -> 128
#define EPSV 1e-5f
#define GCH 64                  // scan chunks
#define TC (SEQ/GCH)            // 16 timesteps per chunk
#define KSPL 8                  // x_proj K-split factor (fp32 partials)
#define OSPL 2                  // out_proj K-split factor (bf16 partials)

typedef unsigned short u16;
typedef unsigned int u32;
typedef __attribute__((ext_vector_type(8))) short bf16x8;
typedef __attribute__((ext_vector_type(4))) short s16x4;
typedef __attribute__((ext_vector_type(4))) float f32x4;

__device__ __forceinline__ u16 f2b(float f) {
    union { float f; unsigned u; } v; v.f = f;
    unsigned r = v.u + 0x7fffu + ((v.u >> 16) & 1u);
    return (u16)(r >> 16);
}
__device__ __forceinline__ float b2f(u16 h) {
    union { unsigned u; float f; } v; v.u = ((unsigned)h) << 16;
    return v.f;
}
__device__ __forceinline__ float silu(float x) {
    return x / (1.f + __expf(-x));
}
__device__ __forceinline__ void gload16(const void* g, void* l) {
    __builtin_amdgcn_global_load_lds(
        (const __attribute__((address_space(1))) void*)g,
        (__attribute__((address_space(3))) void*)l, 16, 0, 0);
}

// ---------------------------------------------------------------------------
// in_proj GEMM: 256x256 8-phase, BK=64, counted vmcnt, XCD swizzle,
// persistent fragments (structure plateau ~44us at K=1024).
// ---------------------------------------------------------------------------
__global__ __launch_bounds__(512, 2)
void gemm256_k(const u16* __restrict__ A, const u16* __restrict__ B,
               u16* __restrict__ C, int K, int ldc)
{
    __shared__ u16 lds[2][2][256 * 64];
    const int tid  = threadIdx.x;
    const int lane = tid & 63;
    const int wid  = tid >> 6;
    const int wr   = wid >> 2;
    const int wc   = wid & 3;
    const int hwid = blockIdx.y * gridDim.x + blockIdx.x;     // 0..255
    const int work = (hwid & 7) * 32 + (hwid >> 3);           // XCD swizzle
    const int row0 = (work >> 4) * 256;
    const int col0 = (work & 15) * 256;
    const int r16   = lane & 15;
    const int khalf = lane >> 4;

    auto ld1 = [&](int buf, int k0, int l) {
        int op = l >> 2;
        int c  = tid + (l & 3) * 512;
        int r  = c >> 3;
        int ds = c & 7;
        int sc = (ds ^ (r & 7)) * 8;
        const u16* src = op ? &B[(size_t)(col0 + r) * K + k0 + sc]
                            : &A[(size_t)(row0 + r) * K + k0 + sc];
        gload16(src, &lds[buf][op][c * 8]);
    };
    // pairs: 0:{A0,A2} 1:{B0,B1} 2:{B2,B3} 3:{A1,A3}
    auto stage2 = [&](int buf, int k0, int pair) {
        if (pair == 0)      { ld1(buf, k0, 0); ld1(buf, k0, 2); }
        else if (pair == 1) { ld1(buf, k0, 4); ld1(buf, k0, 5); }
        else if (pair == 2) { ld1(buf, k0, 6); ld1(buf, k0, 7); }
        else                { ld1(buf, k0, 1); ld1(buf, k0, 3); }
    };
    auto rdA = [&](int buf, int mrow, int ks) -> bf16x8 {
        int row  = wr * 128 + mrow + r16;
        int phys = ((ks << 2) | khalf) ^ (row & 7);
        return *(const bf16x8*)&lds[buf][0][row * 64 + phys * 8];
    };
    auto rdB = [&](int buf, int nrow, int ks) -> bf16x8 {
        int row  = wc * 64 + nrow + r16;
        int phys = ((ks << 2) | khalf) ^ (row & 7);
        return *(const bf16x8*)&lds[buf][1][row * 64 + phys * 8];
    };

    f32x4 acc[8][4];
#pragma unroll
    for (int m = 0; m < 8; ++m)
#pragma unroll
        for (int n = 0; n < 4; ++n)
            acc[m][n] = (f32x4)0.f;

    bf16x8 afA[4][2], afB[4][2], b01[2][2], b23[2][2];

#define PHASE_MFMA(MH, NH, AF, BF) do {                                       \
    asm volatile("s_waitcnt lgkmcnt(0)" ::: "memory");                        \
    __builtin_amdgcn_sched_barrier(0);                                        \
    __builtin_amdgcn_s_setprio(1);                                            \
    _Pragma("unroll")                                                         \
    for (int ks = 0; ks < 2; ++ks)                                            \
        _Pragma("unroll")                                                     \
        for (int m = 0; m < 4; ++m)                                           \
            _Pragma("unroll")                                                 \
            for (int n = 0; n < 2; ++n)                                       \
                acc[(MH)*4+m][(NH)*2+n] =                                     \
                    __builtin_amdgcn_mfma_f32_16x16x32_bf16(                  \
                        AF[m][ks], BF[n][ks], acc[(MH)*4+m][(NH)*2+n],0,0,0); \
    __builtin_amdgcn_s_setprio(0);                                            \
} while (0)

    const int nt = K >> 6;
    stage2(0, 0, 0); stage2(0, 0, 1); stage2(0, 0, 3); stage2(0, 0, 2);
    asm volatile("s_waitcnt vmcnt(4)" ::: "memory");
    __builtin_amdgcn_s_barrier();

    for (int j = 0; j < nt; ++j) {
        const int buf = j & 1;
        const int nb  = buf ^ 1;
        const int k1  = (j + 1) << 6;
        const bool pf = (j + 1 < nt);
        // phase 0: quadrant (0,0); read afA + B01; issue p0^{j+1}
        if (pf) stage2(nb, k1, 0);
#pragma unroll
        for (int m = 0; m < 4; ++m) {
            afA[m][0] = rdA(buf, m * 16, 0); afA[m][1] = rdA(buf, m * 16, 1);
        }
#pragma unroll
        for (int n = 0; n < 2; ++n) {
            b01[n][0] = rdB(buf, n * 16, 0); b01[n][1] = rdB(buf, n * 16, 1);
        }
        __builtin_amdgcn_s_barrier();
        PHASE_MFMA(0, 0, afA, b01);
        if (pf) { asm volatile("s_waitcnt vmcnt(4)" ::: "memory"); }  // p3^j
        else    { asm volatile("s_waitcnt vmcnt(2)" ::: "memory"); }
        __builtin_amdgcn_s_barrier();
        // phase 1: quadrant (1,0); read afB; issue p1^{j+1}
        if (pf) stage2(nb, k1, 1);
#pragma unroll
        for (int m = 0; m < 4; ++m) {
            afB[m][0] = rdA(buf, 64 + m * 16, 0); afB[m][1] = rdA(buf, 64 + m * 16, 1);
        }
        __builtin_amdgcn_s_barrier();
        PHASE_MFMA(1, 0, afB, b01);
        if (pf) { asm volatile("s_waitcnt vmcnt(4)" ::: "memory"); }  // p2^j
        else    { asm volatile("s_waitcnt vmcnt(0)" ::: "memory"); }
        __builtin_amdgcn_s_barrier();
        // phase 2: quadrant (1,1); read B23; issue p3^{j+1}
        if (pf) stage2(nb, k1, 3);
#pragma unroll
        for (int n = 0; n < 2; ++n) {
            b23[n][0] = rdB(buf, 32 + n * 16, 0); b23[n][1] = rdB(buf, 32 + n * 16, 1);
        }
        __builtin_amdgcn_s_barrier();
        PHASE_MFMA(1, 1, afB, b23);
        __builtin_amdgcn_s_barrier();
        // phase 3: quadrant (0,1); no reads; issue p2^{j+1}
        if (pf) stage2(nb, k1, 2);
        PHASE_MFMA(0, 1, afA, b23);
        if (pf) { asm volatile("s_waitcnt vmcnt(4)" ::: "memory"); }  // p0,p1
        __builtin_amdgcn_s_barrier();
    }
#undef PHASE_MFMA

    const int orow = row0 + wr * 128;
    const int ocol = col0 + wc * 64;
#pragma unroll
    for (int am = 0; am < 8; ++am)
#pragma unroll
        for (int an = 0; an < 4; ++an)
#pragma unroll
            for (int r = 0; r < 4; ++r) {
                int rr = orow + am * 16 + khalf * 4 + r;
                int cc = ocol + an * 16 + r16;
                C[(size_t)rr * ldc + cc] = f2b(acc[am][an][r]);
            }
}

// ---------------------------------------------------------------------------
// 128x128 GEMM: 3-buffer pipeline, swizzled.
// EPI: 0 = fp32, 2 = softplus(acc+aux[col])->bf16,
//      4 = split-K partial fp32, 5 = split-K partial bf16
//      (4/5: part = blockIdx.x / NPX, col-tile = % NPX, C += part*pstride)
// ---------------------------------------------------------------------------
template<int EPI, int NPX = 1>
__global__ __launch_bounds__(256)
void gemm_bt(const u16* __restrict__ A, const u16* __restrict__ B,
             void* __restrict__ C, const float* __restrict__ aux,
             int K, int lda, int ldc, size_t pstride)
{
    __shared__ u16 As[3][128 * 32];
    __shared__ u16 Bs[3][128 * 32];
    const int tid  = threadIdx.x;
    const int lane = tid & 63;
    const int w    = tid >> 6;
    const int wr   = w >> 1, wc = w & 1;
    const int row0 = blockIdx.y * 128;
    int col0 = blockIdx.x * 128;
    if (EPI == 4 || EPI == 5) {
        int part = blockIdx.x / NPX;
        col0 = (blockIdx.x % NPX) * 128;
        A += (size_t)part * K;
        B += (size_t)part * K;
        if (EPI == 4) C = (void*)((float*)C + (size_t)part * pstride);
        else          C = (void*)((u16*)C   + (size_t)part * pstride);
    }
    const int r16   = lane & 15;
    const int khalf = lane >> 4;
    const int kslot = khalf ^ ((r16 >> 1) & 3);

    auto stage = [&](int buf, int k0) {
#pragma unroll
        for (int c = 0; c < 2; ++c) {
            int chunk = tid + c * 256;
            int r  = chunk >> 2;
            int j  = chunk & 3;
            int k8 = (j ^ ((r >> 1) & 3)) * 8;
            gload16(&A[(size_t)(row0 + r) * lda + k0 + k8], &As[buf][chunk * 8]);
            gload16(&B[(size_t)(col0 + r) * lda + k0 + k8], &Bs[buf][chunk * 8]);
        }
    };

    f32x4 acc[4][4];
#pragma unroll
    for (int m = 0; m < 4; ++m)
#pragma unroll
        for (int n = 0; n < 4; ++n)
            acc[m][n] = (f32x4)0.f;

    const int nt = K >> 5;
    stage(0, 0);
    if (nt > 1) stage(1, 32);

    int cur = 0, sb = 2;
    for (int t = 0; t < nt; ++t) {
        if (t + 2 < nt) {
            stage(sb, (t + 2) << 5);
            asm volatile("s_waitcnt vmcnt(8)" ::: "memory");
        } else if (t + 1 < nt) {
            asm volatile("s_waitcnt vmcnt(4)" ::: "memory");
        } else {
            asm volatile("s_waitcnt vmcnt(0)" ::: "memory");
        }
        __builtin_amdgcn_s_barrier();

        bf16x8 af[4], bfr[4];
#pragma unroll
        for (int m = 0; m < 4; ++m)
            af[m]  = *(const bf16x8*)&As[cur][(wr * 64 + m * 16 + r16) * 32 + kslot * 8];
#pragma unroll
        for (int n = 0; n < 4; ++n)
            bfr[n] = *(const bf16x8*)&Bs[cur][(wc * 64 + n * 16 + r16) * 32 + kslot * 8];
#pragma unroll
        for (int m = 0; m < 4; ++m)
#pragma unroll
            for (int n = 0; n < 4; ++n)
                acc[m][n] = __builtin_amdgcn_mfma_f32_16x16x32_bf16(
                    af[m], bfr[n], acc[m][n], 0, 0, 0);

        __builtin_amdgcn_sched_barrier(0);
        asm volatile("s_waitcnt lgkmcnt(0)" ::: "memory");
        __builtin_amdgcn_s_barrier();
        cur = (cur == 2) ? 0 : cur + 1;
        sb  = (sb  == 2) ? 0 : sb  + 1;
    }

    const int orow = row0 + wr * 64;
    const int ocol = col0 + wc * 64;
#pragma unroll
    for (int m = 0; m < 4; ++m)
#pragma unroll
        for (int n = 0; n < 4; ++n) {
#pragma unroll
            for (int r = 0; r < 4; ++r) {
                int rr = orow + m * 16 + khalf * 4 + r;
                int cc = ocol + n * 16 + r16;
                float v = acc[m][n][r];
                size_t o = (size_t)rr * ldc + cc;
                if (EPI == 0 || EPI == 4) {
                    ((float*)C)[o] = v;
                } else if (EPI == 5) {
                    ((u16*)C)[o] = f2b(v);
                } else if (EPI == 2) {
                    float x = v + aux[cc];
                    float sp = (x > 20.f) ? x : log1pf(__expf(x));
                    ((u16*)C)[o] = f2b(sp);
                }
            }
        }
}

// ---------------------------------------------------------------------------
// x_proj split-K reduce: ssm = sum of KSPL fp32 partials + bf16 dt-rank cols.
// ---------------------------------------------------------------------------
__global__ __launch_bounds__(256)
void xred_k(const float* __restrict__ part, float* __restrict__ ssm,
            u16* __restrict__ dtr)
{
    int idx = blockIdx.x * 256 + threadIdx.x;
    int row = idx >> 5;
    int col = (idx & 31) * 4;
    size_t o = (size_t)row * XROWS + col;
    const size_t stride = (size_t)TOK * XROWS;
    f32x4 v = *(const f32x4*)&part[o];
#pragma unroll
    for (int p = 1; p < KSPL; ++p)
        v += *(const f32x4*)&part[o + p * stride];
    *(f32x4*)&ssm[o] = v;
    if (col < DT_RANK) {
        s16x4 d;
#pragma unroll
        for (int j = 0; j < 4; ++j) d[j] = (short)f2b(v[j]);
        *(s16x4*)&dtr[(size_t)row * DT_RANK + col] = d;
    }
}

// ---------------------------------------------------------------------------
// RMSNorm (plain): rows of 1024 fp32 -> bf16/fp32.
// ---------------------------------------------------------------------------
template<int OUTBF>
__global__ __launch_bounds__(256)
void rmsnorm_k(const float* __restrict__ in, const float* __restrict__ w,
               void* __restrict__ out)
{
    __shared__ float red[4];
    const int row = blockIdx.x;
    const int tid = threadIdx.x;
    const float* r = in + (size_t)row * D_MODEL;
    f32x4 v = *(const f32x4*)&r[tid * 4];
    float ss = v[0]*v[0] + v[1]*v[1] + v[2]*v[2] + v[3]*v[3];
#pragma unroll
    for (int m = 32; m >= 1; m >>= 1) ss += __shfl_xor(ss, m, 64);
    if ((tid & 63) == 0) red[tid >> 6] = ss;
    __syncthreads();
    if (tid == 0) {
        float s = red[0] + red[1] + red[2] + red[3];
        red[0] = rsqrtf(s / (float)D_MODEL + EPSV);
    }
    __syncthreads();
    float sc = red[0];
    if (OUTBF) {
        u16* o = (u16*)out + (size_t)row * D_MODEL + tid * 4;
#pragma unroll
        for (int j = 0; j < 4; ++j) o[j] = f2b(v[j] * sc * w[tid * 4 + j]);
    } else {
        float* o = (float*)out + (size_t)row * D_MODEL + tid * 4;
#pragma unroll
        for (int j = 0; j < 4; ++j) o[j] = v[j] * sc * w[tid * 4 + j];
    }
}

// ---------------------------------------------------------------------------
// Fused residual + RMSNorm: hn = hin + p0 + p1 (out_proj bf16 partials);
// optionally write hn to hout; write normalized output (bf16 or fp32).
// ---------------------------------------------------------------------------
template<int OUTBF, int WRITEH>
__global__ __launch_bounds__(256)
void rmsnorm_res_k(const float* __restrict__ hin, const u16* __restrict__ p,
                   const float* __restrict__ w, float* __restrict__ hout,
                   void* __restrict__ out)
{
    __shared__ float red[4];
    const int row = blockIdx.x;
    const int tid = threadIdx.x;
    const size_t o4 = (size_t)row * D_MODEL + tid * 4;
    f32x4 v = *(const f32x4*)&hin[o4];
#pragma unroll
    for (int k = 0; k < OSPL; ++k) {
        s16x4 pv = *(const s16x4*)&p[(size_t)k * TOK * D_MODEL + o4];
#pragma unroll
        for (int j = 0; j < 4; ++j) v[j] += b2f((u16)pv[j]);
    }
    if (WRITEH) *(f32x4*)&hout[o4] = v;
    float ss = v[0]*v[0] + v[1]*v[1] + v[2]*v[2] + v[3]*v[3];
#pragma unroll
    for (int m = 32; m >= 1; m >>= 1) ss += __shfl_xor(ss, m, 64);
    if ((tid & 63) == 0) red[tid >> 6] = ss;
    __syncthreads();
    if (tid == 0) {
        float s = red[0] + red[1] + red[2] + red[3];
        red[0] = rsqrtf(s / (float)D_MODEL + EPSV);
    }
    __syncthreads();
    float sc = red[0];
    if (OUTBF) {
        u16* o = (u16*)out + o4;
#pragma unroll
        for (int j = 0; j < 4; ++j) o[j] = f2b(v[j] * sc * w[tid * 4 + j]);
    } else {
        float* o = (float*)out + o4;
#pragma unroll
        for (int j = 0; j < 4; ++j) o[j] = v[j] * sc * w[tid * 4 + j];
    }
}

// ---------------------------------------------------------------------------
// Depthwise causal conv + bias + SiLU, sliding window (4 tokens/block).
// ---------------------------------------------------------------------------
__global__ __launch_bounds__(256)
void conv_silu_k(const u16* __restrict__ projbf, const float* __restrict__ w,
                 const float* __restrict__ bias, u16* __restrict__ ubf)
{
    const int tok0 = blockIdx.x * 4;
    const int t0   = tok0 & (SEQ - 1);
    const int i0   = threadIdx.x * 8;
    float hv[7][8];
#pragma unroll
    for (int m = 0; m < 7; ++m) {
        int tt = t0 - 3 + m;
        if (tt >= 0) {
            bf16x8 v = *(const bf16x8*)&projbf[(size_t)(tok0 - 3 + m) * 4096 + i0];
#pragma unroll
            for (int j = 0; j < 8; ++j) hv[m][j] = b2f((u16)v[j]);
        } else {
#pragma unroll
            for (int j = 0; j < 8; ++j) hv[m][j] = 0.f;
        }
    }
    f32x4 wv[8];
#pragma unroll
    for (int j = 0; j < 8; ++j)
        wv[j] = *(const f32x4*)&w[(i0 + j) * 4];
    float bs[8];
    {
        f32x4 b0 = *(const f32x4*)&bias[i0];
        f32x4 b1 = *(const f32x4*)&bias[i0 + 4];
#pragma unroll
        for (int j = 0; j < 4; ++j) { bs[j] = b0[j]; bs[j + 4] = b1[j]; }
    }
#pragma unroll
    for (int q = 0; q < 4; ++q) {
        bf16x8 o;
#pragma unroll
        for (int j = 0; j < 8; ++j) {
            float acc = bs[j];
#pragma unroll
            for (int k = 0; k < 4; ++k)
                acc += hv[q + k][j] * wv[j][k];
            o[j] = (short)f2b(silu(acc));
        }
        *(bf16x8*)&ubf[(size_t)(tok0 + q) * INTER + i0] = o;
    }
}

// ---------------------------------------------------------------------------
// A_log structure check (fast-path guard).
// ---------------------------------------------------------------------------
__global__ __launch_bounds__(256)
void achk_k(const float* __restrict__ Alog, int* __restrict__ flags)
{
    int idx = blockIdx.x * 256 + threadIdx.x;
    if (idx >= N_LAYERS * INTER * D_STATE) return;
    int l = idx / (INTER * D_STATE);
    int n = idx & (D_STATE - 1);
    float ref = logf((float)(n + 1));
    if (fabsf(Alog[idx] - ref) > 1e-4f) atomicAnd(&flags[l], 0);
}

// ---------------------------------------------------------------------------
// Chunked selective scan, 2 channels per thread (ILP x2, packed u32 loads).
// Fast path: decay exp(dt*a_n) == w^(n+1), w = exp(-dt).
// ---------------------------------------------------------------------------
#define POWCH(W, p) \
    float p##2=(W)*(W), p##3=p##2*(W), p##4=p##2*p##2, p##5=p##4*(W),        \
          p##6=p##4*p##2, p##7=p##4*p##3, p##8=p##4*p##4, p##9=p##8*(W),     \
          p##10=p##8*p##2, p##11=p##8*p##3, p##12=p##8*p##4, p##13=p##8*p##5,\
          p##14=p##8*p##6, p##15=p##8*p##7, p##16=p##8*p##8;

#define SUPD(S, B, du, w1) \
    S[0]=w1*S[0]+du*B[0][0];   S[1]=w1##2*S[1]+du*B[0][1];                   \
    S[2]=w1##3*S[2]+du*B[0][2];  S[3]=w1##4*S[3]+du*B[0][3];                 \
    S[4]=w1##5*S[4]+du*B[1][0];  S[5]=w1##6*S[5]+du*B[1][1];                 \
    S[6]=w1##7*S[6]+du*B[1][2];  S[7]=w1##8*S[7]+du*B[1][3];                 \
    S[8]=w1##9*S[8]+du*B[2][0];  S[9]=w1##10*S[9]+du*B[2][1];                \
    S[10]=w1##11*S[10]+du*B[2][2]; S[11]=w1##12*S[11]+du*B[2][3];            \
    S[12]=w1##13*S[12]+du*B[3][0]; S[13]=w1##14*S[13]+du*B[3][1];            \
    S[14]=w1##15*S[14]+du*B[3][2]; S[15]=w1##16*S[15]+du*B[3][3];

#define YDOT(S, Cv) \
    (S[0]*Cv[0][0]+S[1]*Cv[0][1]+S[2]*Cv[0][2]+S[3]*Cv[0][3]                 \
    +S[4]*Cv[1][0]+S[5]*Cv[1][1]+S[6]*Cv[1][2]+S[7]*Cv[1][3]                 \
    +S[8]*Cv[2][0]+S[9]*Cv[2][1]+S[10]*Cv[2][2]+S[11]*Cv[2][3]               \
    +S[12]*Cv[3][0]+S[13]*Cv[3][1]+S[14]*Cv[3][2]+S[15]*Cv[3][3])

__global__ __launch_bounds__(256)
void scan1_k(const u16* __restrict__ dtbf, const u16* __restrict__ ubf,
             const float* __restrict__ ssm, const float* __restrict__ Alog,
             const int* __restrict__ flag,
             float* __restrict__ cst, float* __restrict__ dts)
{
    __shared__ float Bsh[TC][D_STATE];
    const int tid = threadIdx.x;
    const int i2  = blockIdx.x * 256 + tid;     // channel pair index
    const int c0  = i2 * 2;
    const int g   = blockIdx.y;
    const int b   = blockIdx.z;
    const int t0  = g * TC;
    {
        int t = tid >> 4, n = tid & 15;        // TC*16 = 256
        Bsh[t][n] = ssm[(size_t)(b * SEQ + t0 + t) * XROWS + DT_RANK + n];
    }
    __syncthreads();

    float s0[D_STATE], s1[D_STATE];
#pragma unroll
    for (int n = 0; n < D_STATE; ++n) { s0[n] = 0.f; s1[n] = 0.f; }
    float ds0 = 0.f, ds1 = 0.f;

    const u32* dtp = (const u32*)dtbf + ((size_t)(b * SEQ + t0) * INTER >> 1) + i2;
    const u32* up  = (const u32*)ubf  + ((size_t)(b * SEQ + t0) * INTER >> 1) + i2;

    if (flag[0]) {
#pragma unroll
        for (int t = 0; t < TC; ++t) {
            u32 dp = dtp[(size_t)t * (INTER / 2)];
            u32 uq = up[(size_t)t * (INTER / 2)];
            float dta = b2f((u16)dp), dtb = b2f((u16)(dp >> 16));
            float ua  = b2f((u16)uq), ub  = b2f((u16)(uq >> 16));
            float dua = dta * ua, dub = dtb * ub;
            ds0 += dta; ds1 += dtb;
            float wa = __expf(-dta), wb = __expf(-dtb);
            POWCH(wa, wa) POWCH(wb, wb)
            f32x4 Bq[4];
#pragma unroll
            for (int q = 0; q < 4; ++q) Bq[q] = *(const f32x4*)&Bsh[t][q * 4];
            SUPD(s0, Bq, dua, wa)
            SUPD(s1, Bq, dub, wb)
        }
    } else {
        float a0[D_STATE], a1[D_STATE];
#pragma unroll
        for (int n = 0; n < D_STATE; ++n) {
            a0[n] = -__expf(Alog[(size_t)c0 * D_STATE + n]);
            a1[n] = -__expf(Alog[(size_t)(c0 + 1) * D_STATE + n]);
        }
        for (int t = 0; t < TC; ++t) {
            u32 dp = dtp[(size_t)t * (INTER / 2)];
            u32 uq = up[(size_t)t * (INTER / 2)];
            float dta = b2f((u16)dp), dtb = b2f((u16)(dp >> 16));
            float ua  = b2f((u16)uq), ub  = b2f((u16)(uq >> 16));
            float dua = dta * ua, dub = dtb * ub;
            ds0 += dta; ds1 += dtb;
#pragma unroll
            for (int n = 0; n < D_STATE; ++n) {
                float Bn = Bsh[t][n];
                s0[n] = __expf(dta * a0[n]) * s0[n] + dua * Bn;
                s1[n] = __expf(dtb * a1[n]) * s1[n] + dub * Bn;
            }
        }
    }
    size_t o = ((size_t)(b * GCH + g) * INTER + c0) * D_STATE;
#pragma unroll
    for (int n = 0; n < D_STATE; n += 4) {
        f32x4 v0 = { s0[n], s0[n+1], s0[n+2], s0[n+3] };
        f32x4 v1 = { s1[n], s1[n+1], s1[n+2], s1[n+3] };
        *(f32x4*)&cst[o + n] = v0;
        *(f32x4*)&cst[o + D_STATE + n] = v1;
    }
    size_t od = (size_t)(b * GCH + g) * INTER + c0;
    dts[od] = ds0; dts[od + 1] = ds1;
}

// in-place: cst local chunk-end -> chunk-START states.
__global__ __launch_bounds__(256)
void scan2_k(float* __restrict__ cst, const float* __restrict__ dts,
             const float* __restrict__ Alog)
{
    int idx = blockIdx.x * 256 + threadIdx.x;
    int sub = idx & 3;
    int i   = (idx >> 2) & (INTER - 1);
    int b   = idx >> 13;
    int n0  = sub * 4;
    float a[4];
#pragma unroll
    for (int n = 0; n < 4; ++n)
        a[n] = -__expf(Alog[(size_t)i * D_STATE + n0 + n]);
    f32x4 s = (f32x4)0.f;
    for (int g = 0; g < GCH; ++g) {
        size_t o = ((size_t)(b * GCH + g) * INTER + i) * D_STATE + n0;
        f32x4 tmp = *(const f32x4*)&cst[o];
        *(f32x4*)&cst[o] = s;
        float d = dts[(size_t)(b * GCH + g) * INTER + i];
#pragma unroll
        for (int n = 0; n < 4; ++n)
            s[n] = __expf(a[n] * d) * s[n] + tmp[n];
    }
}

__global__ __launch_bounds__(256)
void scan3_k(const u16* __restrict__ dtbf, const u16* __restrict__ ubf,
             const float* __restrict__ ssm, const u16* __restrict__ projbf,
             const float* __restrict__ Alog, const float* __restrict__ Dp,
             const int* __restrict__ flag,
             const float* __restrict__ sst, u16* __restrict__ ybf)
{
    __shared__ float Bsh[TC][D_STATE];
    __shared__ float Csh[TC][D_STATE];
    const int tid = threadIdx.x;
    const int i2  = blockIdx.x * 256 + tid;
    const int c0  = i2 * 2;
    const int g   = blockIdx.y;
    const int b   = blockIdx.z;
    const int t0  = g * TC;
    {
        int t = tid >> 4, n = tid & 15;
        size_t row = (size_t)(b * SEQ + t0 + t) * XROWS;
        Bsh[t][n] = ssm[row + DT_RANK + n];
        Csh[t][n] = ssm[row + DT_RANK + D_STATE + n];
    }
    __syncthreads();

    const float Da = Dp[c0], Db = Dp[c0 + 1];
    float s0[D_STATE], s1[D_STATE];
    size_t so = ((size_t)(b * GCH + g) * INTER + c0) * D_STATE;
#pragma unroll
    for (int n = 0; n < D_STATE; n += 4) {
        f32x4 v0 = *(const f32x4*)&sst[so + n];
        f32x4 v1 = *(const f32x4*)&sst[so + D_STATE + n];
        s0[n] = v0[0]; s0[n+1] = v0[1]; s0[n+2] = v0[2]; s0[n+3] = v0[3];
        s1[n] = v1[0]; s1[n+1] = v1[1]; s1[n+2] = v1[2]; s1[n+3] = v1[3];
    }

    const u32* dtp = (const u32*)dtbf + ((size_t)(b * SEQ + t0) * INTER >> 1) + i2;
    const u32* up  = (const u32*)ubf  + ((size_t)(b * SEQ + t0) * INTER >> 1) + i2;
    const u32* gp  = (const u32*)projbf + (((size_t)(b * SEQ + t0) * 4096 + INTER) >> 1) + i2;
    u32*       yp  = (u32*)ybf + ((size_t)(b * SEQ + t0) * INTER >> 1) + i2;

    if (flag[0]) {
#pragma unroll
        for (int t = 0; t < TC; ++t) {
            u32 dp = dtp[(size_t)t * (INTER / 2)];
            u32 uq = up[(size_t)t * (INTER / 2)];
            u32 gq = gp[(size_t)t * (4096 / 2)];
            float dta = b2f((u16)dp), dtb = b2f((u16)(dp >> 16));
            float ua  = b2f((u16)uq), ub  = b2f((u16)(uq >> 16));
            float ga  = b2f((u16)gq), gb  = b2f((u16)(gq >> 16));
            float dua = dta * ua, dub = dtb * ub;
            float wa = __expf(-dta), wb = __expf(-dtb);
            POWCH(wa, wa) POWCH(wb, wb)
            f32x4 Bq[4], Cq[4];
#pragma unroll
            for (int q = 0; q < 4; ++q) {
                Bq[q] = *(const f32x4*)&Bsh[t][q * 4];
                Cq[q] = *(const f32x4*)&Csh[t][q * 4];
            }
            SUPD(s0, Bq, dua, wa)
            SUPD(s1, Bq, dub, wb)
            float y0 = YDOT(s0, Cq);
            float y1 = YDOT(s1, Cq);
            y0 = (y0 + Da * ua) * silu(ga);
            y1 = (y1 + Db * ub) * silu(gb);
            yp[(size_t)t * (INTER / 2)] = (u32)f2b(y0) | ((u32)f2b(y1) << 16);
        }
    } else {
        float a0[D_STATE], a1[D_STATE];
#pragma unroll
        for (int n = 0; n < D_STATE; ++n) {
            a0[n] = -__expf(Alog[(size_t)c0 * D_STATE + n]);
            a1[n] = -__expf(Alog[(size_t)(c0 + 1) * D_STATE + n]);
        }
        for (int t = 0; t < TC; ++t) {
            u32 dp = dtp[(size_t)t * (INTER / 2)];
            u32 uq = up[(size_t)t * (INTER / 2)];
            u32 gq = gp[(size_t)t * (4096 / 2)];
            float dta = b2f((u16)dp), dtb = b2f((u16)(dp >> 16));
            float ua  = b2f((u16)uq), ub  = b2f((u16)(uq >> 16));
            float ga  = b2f((u16)gq), gb  = b2f((u16)(gq >> 16));
            float dua = dta * ua, dub = dtb * ub;
            float y0 = 0.f, y1 = 0.f;
#pragma unroll
            for (int n = 0; n < D_STATE; ++n) {
                float Bn = Bsh[t][n], Cn = Csh[t][n];
                s0[n] = __expf(dta * a0[n]) * s0[n] + dua * Bn;
                s1[n] = __expf(dtb * a1[n]) * s1[n] + dub * Bn;
                y0 += s0[n] * Cn; y1 += s1[n] * Cn;
            }
            y0 = (y0 + Da * ua) * silu(ga);
            y1 = (y1 + Db * ub) * silu(gb);
            yp[(size_t)t * (INTER / 2)] = (u32)f2b(y0) | ((u32)f2b(y1) << 16);
        }
    }
}

// ---------------------------------------------------------------------------
// Merged weight conversion fp32 -> bf16 (inw | dtw | outw | xw-pad).
// ---------------------------------------------------------------------------
#define INW_N  (N_LAYERS * 4096 * 1024)
#define DTW_N  (N_LAYERS * INTER * DT_RANK)
#define OUTW_N (N_LAYERS * D_MODEL * INTER)
#define XWP_N  (N_LAYERS * XROWS * INTER)
__global__ __launch_bounds__(256)
void cvtall_k(const float* __restrict__ in_w, const float* __restrict__ dt_w,
              const float* __restrict__ out_w, const float* __restrict__ xw,
              u16* __restrict__ inw_bf, u16* __restrict__ dtw_bf,
              u16* __restrict__ outw_bf, u16* __restrict__ xw_bf)
{
    int idx = (blockIdx.x * 256 + threadIdx.x) * 4;
    const float* src;
    u16* dst;
    int i;
    if (idx < INW_N) {
        src = in_w; dst = inw_bf; i = idx;
    } else if (idx < INW_N + DTW_N) {
        src = dt_w; dst = dtw_bf; i = idx - INW_N;
    } else if (idx < INW_N + DTW_N + OUTW_N) {
        src = out_w; dst = outw_bf; i = idx - INW_N - DTW_N;
    } else {
        i = idx - INW_N - DTW_N - OUTW_N;
        if (i >= XWP_N) return;
        int l = i / (XROWS * INTER);
        int r = (i >> 11) & (XROWS - 1);
        int c = i & (INTER - 1);
        s16x4 d;
        if (r < 96) {
            f32x4 v = *(const f32x4*)&xw[((size_t)l * 96 + r) * INTER + c];
#pragma unroll
            for (int j = 0; j < 4; ++j) d[j] = (short)f2b(v[j]);
        } else {
            d = (s16x4)0;
        }
        *(s16x4*)&xw_bf[i] = d;
        return;
    }
    f32x4 v = *(const f32x4*)&src[i];
    s16x4 d;
#pragma unroll
    for (int j = 0; j < 4; ++j) d[j] = (short)f2b(v[j]);
    *(s16x4*)&dst[i] = d;
}

// ---------------------------------------------------------------------------
extern "C" void kernel_launch(void* const* d_in, const int* in_sizes, int n_in,
                              void* d_out, int out_size, void* d_ws, size_t ws_size,
                              hipStream_t stream)
{
    const float* x      = (const float*)d_in[0];
    const float* in_w   = (const float*)d_in[1];
    const float* conv_w = (const float*)d_in[2];
    const float* conv_b = (const float*)d_in[3];
    const float* x_w    = (const float*)d_in[4];
    const float* dt_w   = (const float*)d_in[5];
    const float* dt_b   = (const float*)d_in[6];
    const float* A_log  = (const float*)d_in[7];
    const float* Dp     = (const float*)d_in[8];
    const float* out_w  = (const float*)d_in[9];
    const float* norm_w = (const float*)d_in[10];
    const float* norm_f = (const float*)d_in[11];

    char* ws = (char*)d_ws;
    size_t off = 0;
    auto alloc = [&](size_t bytes) { char* p = ws + off; off += (bytes + 255) & ~(size_t)255; return p; };

    u16*   inw_bf  = (u16*)  alloc((size_t)N_LAYERS * 4096 * 1024 * 2);
    u16*   xw_bf   = (u16*)  alloc((size_t)N_LAYERS * XROWS * INTER * 2);
    u16*   dtw_bf  = (u16*)  alloc((size_t)N_LAYERS * INTER * DT_RANK * 2);
    u16*   outw_bf = (u16*)  alloc((size_t)N_LAYERS * D_MODEL * INTER * 2);
    float* h       = (float*)alloc((size_t)TOK * D_MODEL * 4);
    u16*   xn_bf   = (u16*)  alloc((size_t)TOK * D_MODEL * 2);
    u16*   proj_bf = (u16*)  alloc((size_t)TOK * 4096 * 2);
    u16*   u_bf    = (u16*)  alloc((size_t)TOK * INTER * 2);
    float* ssm     = (float*)alloc((size_t)TOK * XROWS * 4);
    // shared partials buffer: x_proj fp32 partials (KSPL x 2.1MB = 16.8MB)
    // and out_proj bf16 partials (OSPL x 8.4MB = 16.8MB) - disjoint lifetimes.
    float* parts   = (float*)alloc((size_t)KSPL * TOK * XROWS * 4);
    u16*   partsbf = (u16*)parts;
    u16*   dtr_bf  = (u16*)  alloc((size_t)TOK * DT_RANK * 2);
    u16*   dt_bf   = (u16*)  alloc((size_t)TOK * INTER * 2);
    u16*   y_bf    = (u16*)  alloc((size_t)TOK * INTER * 2);
    float* cst     = (float*)alloc((size_t)B_SZ * GCH * INTER * D_STATE * 4);
    float* dts     = (float*)alloc((size_t)B_SZ * GCH * INTER * 4);
    int*   aflags  = (int*)  alloc(N_LAYERS * sizeof(int));
    (void)ws_size; (void)n_in; (void)in_sizes; (void)out_size;

    // weight conversion (merged) + A_log structure check
    {
        int total = INW_N + DTW_N + OUTW_N + XWP_N;
        cvtall_k<<<(total / 4 + 255) / 256, 256, 0, stream>>>(
            in_w, dt_w, out_w, x_w, inw_bf, dtw_bf, outw_bf, xw_bf);
        hipMemsetAsync(aflags, 0xFF, N_LAYERS * sizeof(int), stream);
        int na = N_LAYERS * INTER * D_STATE;
        achk_k<<<(na + 255) / 256, 256, 0, stream>>>(A_log, aflags);
    }

    for (int l = 0; l < N_LAYERS; ++l) {
        // 1. residual + rmsnorm -> xn_bf (and h update for l>=1)
        if (l == 0)
            rmsnorm_k<1><<<TOK, 256, 0, stream>>>(x, norm_w, xn_bf);
        else
            rmsnorm_res_k<1, 1><<<TOK, 256, 0, stream>>>(
                (l == 1) ? x : h, partsbf, norm_w + (size_t)l * D_MODEL, h, xn_bf);
        // 2. in_proj (256^2 8-phase, counted vmcnt + persistent frags)
        gemm256_k<<<dim3(16, 16), 512, 0, stream>>>(
            xn_bf, inw_bf + (size_t)l * 4096 * 1024, proj_bf, 1024, 4096);
        // 3. conv + silu (sliding window) -> u_bf
        conv_silu_k<<<TOK / 4, 256, 0, stream>>>(
            proj_bf, conv_w + (size_t)l * INTER * D_CONV, conv_b + (size_t)l * INTER, u_bf);
        // 4. x_proj split-K(8) -> fp32 partials
        gemm_bt<4, 1><<<dim3(KSPL, 32), 256, 0, stream>>>(
            u_bf, xw_bf + (size_t)l * XROWS * INTER, parts, nullptr,
            INTER / KSPL, INTER, XROWS, (size_t)TOK * XROWS);
        // 4b. reduce partials -> ssm fp32 + dtr bf16
        xred_k<<<(TOK * 32) / 256, 256, 0, stream>>>(parts, ssm, dtr_bf);
        // 5. dt_proj + softplus -> dt_bf [4096,2048]
        gemm_bt<2><<<dim3(16, 32), 256, 0, stream>>>(
            dtr_bf, dtw_bf + (size_t)l * INTER * DT_RANK, dt_bf,
            dt_b + (size_t)l * INTER, DT_RANK, DT_RANK, INTER, 0);
        // 6. chunked scan (+ skip + gate) -> y_bf
        scan1_k<<<dim3(INTER / 512, GCH, B_SZ), 256, 0, stream>>>(
            dt_bf, u_bf, ssm, A_log + (size_t)l * INTER * D_STATE, aflags + l, cst, dts);
        scan2_k<<<(B_SZ * INTER * 4) / 256, 256, 0, stream>>>(
            cst, dts, A_log + (size_t)l * INTER * D_STATE);
        scan3_k<<<dim3(INTER / 512, GCH, B_SZ), 256, 0, stream>>>(
            dt_bf, u_bf, ssm, proj_bf, A_log + (size_t)l * INTER * D_STATE,
            Dp + (size_t)l * INTER, aflags + l, cst, y_bf);
        // 7. out_proj split-K(2) -> bf16 partials (consumed by rmsnorm_res)
        gemm_bt<5, 8><<<dim3(OSPL * 8, 32), 256, 0, stream>>>(
            y_bf, outw_bf + (size_t)l * D_MODEL * INTER, partsbf, nullptr,
            INTER / OSPL, INTER, D_MODEL, (size_t)TOK * D_MODEL);
    }
    // final residual + rmsnorm -> d_out (fp32)
    rmsnorm_res_k<0, 0><<<TOK, 256, 0, stream>>>(
        h, partsbf, norm_f, nullptr, d_out);
}